// Round 21
// baseline (172.438 us; speedup 1.0000x reference)
//
#include <hip/hip_runtime.h>
#include <math.h>

#define N_PIX 4096
#define CCH 64

typedef __attribute__((ext_vector_type(8))) short short8;
typedef __attribute__((ext_vector_type(4))) float f32x4;
typedef __attribute__((ext_vector_type(16))) float f32x16;

#define EXP2C 0.18033688f  // 0.125 * log2(e)

// LDS tiles are [rows][68] floats; XOR-swizzle the 4-float granule by (row>>2)&7
// so that 4-row-strided b128 reads spread across bank groups (else 8-way conflict).
__device__ __forceinline__ int swz(int row, int col) {
  return row * 68 + (col ^ (((row >> 2) & 7) << 2));
}

__device__ __forceinline__ float fget(const float4& v, int j) {
  return ((const float*)&v)[j];
}

__device__ __forceinline__ unsigned short f2bf(float f) {
  unsigned u = __float_as_uint(f);
  unsigned r = (u + 0x7fff + ((u >> 16) & 1)) >> 16;
  return (unsigned short)r;
}
__device__ __forceinline__ float bf2f(unsigned short h) {
  return __uint_as_float((unsigned)h << 16);
}

// raw-rate exp2 (single v_exp_f32); inputs here are bounded (|z|<~8, lg2w ~ -12)
__device__ __forceinline__ float fexp2(float x) {
#if __has_builtin(__builtin_amdgcn_exp2f)
  return __builtin_amdgcn_exp2f(x);
#else
  return exp2f(x);
#endif
}

// async global->LDS, 16B per lane. Builtin path: LDS dest = wave-uniform base +
// lane*16 (m104); GLOBAL SOURCE IS PER-LANE - caller must add lane offset.
__device__ __forceinline__ void gll16(const unsigned short* g, unsigned short* lbase,
                                      int lane) {
#if __has_builtin(__builtin_amdgcn_global_load_lds)
  (void)lane;
  __builtin_amdgcn_global_load_lds(
      (const __attribute__((address_space(1))) void*)g,
      (__attribute__((address_space(3))) void*)lbase, 16, 0, 0);
#else
  *(short8*)(lbase + lane * 8) = *(const short8*)g;
#endif
}

// ---------------- weight prep: fold conv weights into wq|wk|wv (+ beff slice) -------
// Grid (3, 26): t<25 -> Weff tap-GEMM; t==25 -> effective bias for this 'which'.
__global__ __launch_bounds__(256) void prep_kernel(
    const float* __restrict__ w1, const float* __restrict__ w3,
    const float* __restrict__ w5, const float* __restrict__ wq,
    const float* __restrict__ wk, const float* __restrict__ wv,
    const float* __restrict__ b1, const float* __restrict__ b3,
    const float* __restrict__ b5, const float* __restrict__ bq,
    const float* __restrict__ bk, const float* __restrict__ bv,
    unsigned short* __restrict__ Bfh, unsigned short* __restrict__ Bfl,
    float* __restrict__ beff) {
  __shared__ float At[64 * 68];  // A[i][o] = wconv[o,i,tap]
  __shared__ float Bt[64 * 68];  // B[o][em] = Wsel[rowbase+o][em]
  const int which = blockIdx.x, t = blockIdx.y;
  const float* Wsel = which == 0 ? wq : (which == 1 ? wk : wv);
  const int tid = threadIdx.x, tx = tid & 15, ty = tid >> 4;
  if (t == 25) {  // beff slice: beff[which*64+e] = bcat[e] + sum_row bconv*Wcat
    if (tid < 64) {
      const float* bsel = which == 0 ? bq : (which == 1 ? bk : bv);
      float s = bsel[tid];
      for (int row = 0; row < 192; ++row) {
        const float bc = row < 64 ? b1[row] : (row < 128 ? b3[row - 64] : b5[row - 128]);
        s += bc * Wsel[row * 64 + tid];
      }
      beff[which * 64 + tid] = s;
    }
    return;
  }
  const int ky = t / 5, kx = t % 5;
  const bool in3 = (ky >= 1 && ky <= 3 && kx >= 1 && kx <= 3);
  const bool c1 = (t == 12);
  const int t3 = (ky - 1) * 3 + (kx - 1);
  float acc[4][4];
#pragma unroll
  for (int i = 0; i < 4; ++i)
#pragma unroll
    for (int j = 0; j < 4; ++j) acc[i][j] = 0.f;
  const int npass = 1 + (in3 ? 1 : 0) + (c1 ? 1 : 0);
  for (int pass = 0; pass < npass; ++pass) {
    const int kind = pass == 0 ? 0 : (pass == 1 && in3 ? 1 : 2);
    const int rowbase = kind == 0 ? 128 : (kind == 1 ? 64 : 0);
    __syncthreads();
    for (int v = tid; v < 4096; v += 256) {
      const int i = v & 63, o = v >> 6;
      float a;
      if (kind == 0) a = w5[(size_t)(o * 64 + i) * 25 + t];
      else if (kind == 1) a = w3[(size_t)(o * 64 + i) * 9 + t3];
      else a = w1[o * 64 + i];
      At[swz(i, o)] = a;
    }
    for (int v = tid; v < 1024; v += 256) {
      const int row = v >> 4, c4 = (v & 15) * 4;
      *(float4*)&Bt[swz(row, c4)] = *(const float4*)(Wsel + (rowbase + row) * 64 + c4);
    }
    __syncthreads();
#pragma unroll
    for (int o4 = 0; o4 < 16; ++o4) {
      float4 a[4], b[4];
#pragma unroll
      for (int i = 0; i < 4; ++i) a[i] = *(const float4*)&At[swz(ty * 4 + i, o4 * 4)];
#pragma unroll
      for (int u = 0; u < 4; ++u) b[u] = *(const float4*)&Bt[swz(o4 * 4 + u, tx * 4)];
#pragma unroll
      for (int i = 0; i < 4; ++i)
#pragma unroll
        for (int j = 0; j < 4; ++j)
#pragma unroll
          for (int u = 0; u < 4; ++u)
            acc[i][j] = fmaf(fget(a[i], u), fget(b[u], j), acc[i][j]);
    }
  }
#pragma unroll
  for (int ii = 0; ii < 4; ++ii) {
    const int i = ty * 4 + ii;
    const int s = i >> 5, lg = (i >> 3) & 3, j = i & 7;
#pragma unroll
    for (int jj = 0; jj < 4; ++jj) {
      const int em = tx * 4 + jj;
      const int q = which * 4 + (em >> 4), lr = em & 15;
      const size_t off = ((size_t)(t * 12 + q) * 2 + s) * 512 + (lg * 16 + lr) * 8 + j;
      const float val = acc[ii][jj];
      const unsigned short h = f2bf(val);
      Bfh[off] = h;
      Bfl[off] = f2bf(val - bf2f(h));
    }
  }
}

// ---------------- x transpose: [b][c][y][x] fp32 -> Xt[b][68][72][64] bf16 hi/lo -----
__global__ __launch_bounds__(256) void xpose_kernel(const float* __restrict__ x,
                                                    unsigned short* __restrict__ Xth,
                                                    unsigned short* __restrict__ Xtl) {
  __shared__ float t[64][65];
  const int yp = blockIdx.x;  // 0..67
  const int b = blockIdx.y;
  const int tid = threadIdx.x;
  const size_t rowbase = ((size_t)b * 68 + yp) * 72 * 64;  // ushort index
  short8 z8 = {0, 0, 0, 0, 0, 0, 0, 0};
  if (yp < 2 || yp >= 66) {
    short8* ph = (short8*)(Xth + rowbase);
    short8* pl = (short8*)(Xtl + rowbase);
    for (int v = tid; v < 576; v += 256) {  // 72*64/8
      ph[v] = z8;
      pl[v] = z8;
    }
    return;
  }
  const int y = yp - 2;
  for (int it = 0; it < 16; ++it) {
    const int v = it * 256 + tid;
    const int c = v >> 6, xx = v & 63;
    t[xx][c] = x[(((size_t)b * 64 + c) * 64 + y) * 64 + xx];
  }
  for (int s = tid; s < 64; s += 256) {
    const int col = s >> 3;
    const int xp = col < 2 ? col : col + 64;
    const size_t o = rowbase + (size_t)xp * 64 + (s & 7) * 8;
    *(short8*)(Xth + o) = z8;
    *(short8*)(Xtl + o) = z8;
  }
  __syncthreads();
  for (int it = 0; it < 16; ++it) {
    const int v = it * 256 + tid;
    const int xx = v >> 6, c = v & 63;
    const float val = t[xx][c];
    const unsigned short h = f2bf(val);
    const unsigned short lo = f2bf(val - bf2f(h));
    const int xp = xx + 2;
    const size_t idx = rowbase + (size_t)xp * 64 + (c ^ ((xp & 7) << 3));
    Xth[idx] = h;
    Xtl[idx] = lo;
  }
}

// ---------------- fused im2col GEMM: Xt -> Q(hi/lo), K(hi/lo), V ----------------
// Grid (64 tiles, 4 b, 3 z): block 256 = 4 waves. Wave wv owns quadrant
// qd = z*4+wv x ALL 64 pixels; 768 blocks -> 3 blocks/CU hides B latency.
__global__ __launch_bounds__(256) void fused_qkv_kernel(
    const unsigned short* __restrict__ Xth, const unsigned short* __restrict__ Xtl,
    const unsigned short* __restrict__ Bfh, const unsigned short* __restrict__ Bfl,
    const float* __restrict__ beff, unsigned short* __restrict__ Qhi,
    unsigned short* __restrict__ Qlo, unsigned short* __restrict__ Khi,
    unsigned short* __restrict__ Klo, float* __restrict__ Vm) {
  __shared__ unsigned short Lh[192 * 64];  // [12 rows][16 px][64 ch] = 24KB
  __shared__ unsigned short Ll[192 * 64];
  const int b = blockIdx.y, sb = blockIdx.x;
  const int y0 = (sb >> 3) * 8, x0 = (sb & 7) * 8;
  const int tid = threadIdx.x, wv = tid >> 6, l = tid & 63;
  const int lr = l & 15, lg = l >> 4;
  const int qd = blockIdx.z * 4 + wv;  // this wave's output quadrant (0..11)
#pragma unroll
  for (int rr = 0; rr < 3; ++rr) {
    const int py = wv * 3 + rr;
    const size_t src = (((size_t)b * 68 + y0 + py) * 72 + x0) * 64 + (size_t)l * 8;
    gll16(Xth + src, &Lh[py * 1024], l);
    gll16(Xth + src + 512, &Lh[py * 1024 + 512], l);
    gll16(Xtl + src, &Ll[py * 1024], l);
    gll16(Xtl + src + 512, &Ll[py * 1024 + 512], l);
  }
  __syncthreads();
  f32x4 acc[4];
#pragma unroll
  for (int pg = 0; pg < 4; ++pg) acc[pg] = (f32x4){0.f, 0.f, 0.f, 0.f};
  for (int ky = 0; ky < 5; ++ky) {
    for (int kx = 0; kx < 5; ++kx) {
      const int t = ky * 5 + kx;
      const size_t f = ((size_t)(t * 12 + qd)) * 2;
      const short8 bh0 = *(const short8*)&Bfh[f * 512 + l * 8];
      const short8 bh1 = *(const short8*)&Bfh[(f + 1) * 512 + l * 8];
      const short8 bl0 = *(const short8*)&Bfl[f * 512 + l * 8];
      const short8 bl1 = *(const short8*)&Bfl[(f + 1) * 512 + l * 8];
#pragma unroll
      for (int pg = 0; pg < 4; ++pg) {
        const int p = pg * 16 + lr;
        const int prt = ((p >> 3) + ky) * 16 + (p & 7) + kx;
        const int rb = prt * 64, sw = (prt & 7) << 3;
        const short8 ah0 = *(const short8*)&Lh[rb + ((lg * 8) ^ sw)];
        const short8 ah1 = *(const short8*)&Lh[rb + ((32 + lg * 8) ^ sw)];
        const short8 al0 = *(const short8*)&Ll[rb + ((lg * 8) ^ sw)];
        const short8 al1 = *(const short8*)&Ll[rb + ((32 + lg * 8) ^ sw)];
        acc[pg] = __builtin_amdgcn_mfma_f32_16x16x32_bf16(ah0, bh0, acc[pg], 0, 0, 0);
        acc[pg] = __builtin_amdgcn_mfma_f32_16x16x32_bf16(ah1, bh1, acc[pg], 0, 0, 0);
        acc[pg] = __builtin_amdgcn_mfma_f32_16x16x32_bf16(al0, bh0, acc[pg], 0, 0, 0);
        acc[pg] = __builtin_amdgcn_mfma_f32_16x16x32_bf16(al1, bh1, acc[pg], 0, 0, 0);
        acc[pg] = __builtin_amdgcn_mfma_f32_16x16x32_bf16(ah0, bl0, acc[pg], 0, 0, 0);
        acc[pg] = __builtin_amdgcn_mfma_f32_16x16x32_bf16(ah1, bl1, acc[pg], 0, 0, 0);
      }
    }
  }
  const size_t base = (size_t)b * N_PIX;
  {
    const int e = qd * 16 + lr;
    const int which = e >> 6, em = e & 63;
    const float be = beff[e];
#pragma unroll
    for (int pg = 0; pg < 4; ++pg) {
#pragma unroll
      for (int r = 0; r < 4; ++r) {
        const int pp = pg * 16 + lg * 4 + r;
        const int n = (y0 + (pp >> 3)) * 64 + x0 + (pp & 7);
        const float val = acc[pg][r] + be;
        const size_t off = (base + n) * 64 + em;
        if (which == 2) {
          Vm[off] = val;
        } else {
          const unsigned short h = f2bf(val);
          const unsigned short lo = f2bf(val - bf2f(h));
          if (which == 0) {
            Qhi[off] = h;
            Qlo[off] = lo;
          } else {
            Khi[off] = h;
            Klo[off] = lo;
          }
        }
      }
    }
  }
}

// ---------------- sweep 1: row sums of exp(z), LDS-staged K, 4-chain MFMA ----------
__global__ __launch_bounds__(256) void qk_s_kernel(
    const unsigned short* __restrict__ Qhi, const unsigned short* __restrict__ Qlo,
    const unsigned short* __restrict__ Khi, const unsigned short* __restrict__ Klo,
    float* __restrict__ s_part) {
  __shared__ unsigned short Kst[2][2][2048];  // [buf][hi/lo][32*64]
  const int b = blockIdx.z, kc = blockIdx.y, q0 = blockIdx.x * 128;
  const int tid = threadIdx.x, wv = tid >> 6, l = tid & 63;
  const int lr = l & 31, lh = l >> 5;
  const size_t base = (size_t)b * N_PIX;
  const size_t qoff = (base + q0 + wv * 32 + lr) * 64 + lh * 8;
  short8 qh[4], ql[4];
#pragma unroll
  for (int f = 0; f < 4; ++f) {
    qh[f] = *(const short8*)(Qhi + qoff + f * 16);
    ql[f] = *(const short8*)(Qlo + qoff + f * 16);
  }
  const int srow = tid >> 3;
  const int gcu = ((tid & 7) * 8) ^ ((srow & 7) << 3);
  const unsigned short* Ksh = Khi + (base + kc * 512 + srow) * 64 + gcu;
  const unsigned short* Ksl = Klo + (base + kc * 512 + srow) * 64 + gcu;
  float racc[16];
#pragma unroll
  for (int r = 0; r < 16; ++r) racc[r] = 0.f;

#define STAGE(bb, t)                                   \
  {                                                    \
    const size_t go_ = (size_t)(t) * 2048;             \
    gll16(Ksh + go_, &Kst[bb][0][wv * 512], l);        \
    gll16(Ksl + go_, &Kst[bb][1][wv * 512], l);        \
  }
// four independent accumulator chains (one per K-fragment) -> dep depth 3
#define COMP(bb)                                                                     \
  {                                                                                  \
    short8 kh_[4], kl_[4];                                                           \
    const int rb_ = lr * 64, sw_ = (lr & 7) << 3;                                    \
    _Pragma("unroll") for (int f = 0; f < 4; ++f) {                                  \
      const int c_ = rb_ + ((lh * 8 + f * 16) ^ sw_);                                \
      kh_[f] = *(const short8*)&Kst[bb][0][c_];                                      \
      kl_[f] = *(const short8*)&Kst[bb][1][c_];                                      \
    }                                                                                \
    f32x16 a0, a1, a2, a3;                                                           \
    _Pragma("unroll") for (int r = 0; r < 16; ++r) {                                 \
      a0[r] = 0.f; a1[r] = 0.f; a2[r] = 0.f; a3[r] = 0.f;                            \
    }                                                                                \
    a0 = __builtin_amdgcn_mfma_f32_32x32x16_bf16(qh[0], kh_[0], a0, 0, 0, 0);        \
    a1 = __builtin_amdgcn_mfma_f32_32x32x16_bf16(qh[1], kh_[1], a1, 0, 0, 0);        \
    a2 = __builtin_amdgcn_mfma_f32_32x32x16_bf16(qh[2], kh_[2], a2, 0, 0, 0);        \
    a3 = __builtin_amdgcn_mfma_f32_32x32x16_bf16(qh[3], kh_[3], a3, 0, 0, 0);        \
    a0 = __builtin_amdgcn_mfma_f32_32x32x16_bf16(ql[0], kh_[0], a0, 0, 0, 0);        \
    a1 = __builtin_amdgcn_mfma_f32_32x32x16_bf16(ql[1], kh_[1], a1, 0, 0, 0);        \
    a2 = __builtin_amdgcn_mfma_f32_32x32x16_bf16(ql[2], kh_[2], a2, 0, 0, 0);        \
    a3 = __builtin_amdgcn_mfma_f32_32x32x16_bf16(ql[3], kh_[3], a3, 0, 0, 0);        \
    a0 = __builtin_amdgcn_mfma_f32_32x32x16_bf16(qh[0], kl_[0], a0, 0, 0, 0);        \
    a1 = __builtin_amdgcn_mfma_f32_32x32x16_bf16(qh[1], kl_[1], a1, 0, 0, 0);        \
    a2 = __builtin_amdgcn_mfma_f32_32x32x16_bf16(qh[2], kl_[2], a2, 0, 0, 0);        \
    a3 = __builtin_amdgcn_mfma_f32_32x32x16_bf16(qh[3], kl_[3], a3, 0, 0, 0);        \
    _Pragma("unroll") for (int r = 0; r < 16; ++r)                                   \
        racc[r] += fexp2(((a0[r] + a1[r]) + (a2[r] + a3[r])) * EXP2C);               \
  }

  STAGE(0, 0);
  __syncthreads();
  int bu = 0;
  for (int t = 0; t < 16; ++t) {
    if (t < 15) STAGE(bu ^ 1, t + 1);
    COMP(bu);
    __syncthreads();
    bu ^= 1;
  }
#undef STAGE
#undef COMP
#pragma unroll
  for (int r = 0; r < 16; ++r)
#pragma unroll
    for (int m = 1; m < 32; m <<= 1) racc[r] += __shfl_xor(racc[r], m);
  if (lr == 0) {
#pragma unroll
    for (int r = 0; r < 16; ++r) {
      const int row = (r & 3) + 8 * (r >> 2) + 4 * lh;
      s_part[((size_t)(b * 8 + kc) << 12) + q0 + wv * 32 + row] = racc[r];
    }
  }
}

// ---------------- sweep 2: weighted col sums + fused combine (grid 32x8x4) ---------
// Prologue: each block computes lg2w for its 512 q-rows from s_part (redundant,
// ~2KB of loads); blockIdx.x==0 blocks also write invs for attn_out.
__global__ __launch_bounds__(256) void colsum_kernel2(
    const unsigned short* __restrict__ Qhi, const unsigned short* __restrict__ Qlo,
    const unsigned short* __restrict__ Khi, const unsigned short* __restrict__ Klo,
    const float* __restrict__ s_part, float* __restrict__ invs,
    float* __restrict__ cs_part) {
  __shared__ unsigned short Qst[2][2][2048];
  __shared__ float lg2wl[512];
  const int b = blockIdx.z, qc = blockIdx.y, k0 = blockIdx.x * 128;
  const int tid = threadIdx.x, wv = tid >> 6, l = tid & 63;
  const int lr = l & 31, lh = l >> 5;
  const size_t base = (size_t)b * N_PIX;
  const size_t koff = (base + k0 + wv * 32 + lr) * 64 + lh * 8;
  short8 kh[4], kl[4];
#pragma unroll
  for (int f = 0; f < 4; ++f) {
    kh[f] = *(const short8*)(Khi + koff + f * 16);
    kl[f] = *(const short8*)(Klo + koff + f * 16);
  }
  const int srow = tid >> 3;
  const int gcu = ((tid & 7) * 8) ^ ((srow & 7) << 3);
  const unsigned short* Qsh = Qhi + (base + qc * 512 + srow) * 64 + gcu;
  const unsigned short* Qsl = Qlo + (base + qc * 512 + srow) * 64 + gcu;
  float kacc[16];
#pragma unroll
  for (int r = 0; r < 16; ++r) kacc[r] = 0.f;

#define STAGE(bb, t)                                   \
  {                                                    \
    const size_t go_ = (size_t)(t) * 2048;             \
    gll16(Qsh + go_, &Qst[bb][0][wv * 512], l);        \
    gll16(Qsl + go_, &Qst[bb][1][wv * 512], l);        \
  }
#define COMP(bb, t_)                                                                 \
  {                                                                                  \
    const float lw_ = lg2wl[(t_) * 32 + lr];                                         \
    short8 qh_[4], ql_[4];                                                           \
    const int rb_ = lr * 64, sw_ = (lr & 7) << 3;                                    \
    _Pragma("unroll") for (int f = 0; f < 4; ++f) {                                  \
      const int c_ = rb_ + ((lh * 8 + f * 16) ^ sw_);                                \
      qh_[f] = *(const short8*)&Qst[bb][0][c_];                                      \
      ql_[f] = *(const short8*)&Qst[bb][1][c_];                                      \
    }                                                                                \
    f32x16 a0, a1, a2, a3;                                                           \
    _Pragma("unroll") for (int r = 0; r < 16; ++r) {                                 \
      a0[r] = 0.f; a1[r] = 0.f; a2[r] = 0.f; a3[r] = 0.f;                            \
    }                                                                                \
    a0 = __builtin_amdgcn_mfma_f32_32x32x16_bf16(kh[0], qh_[0], a0, 0, 0, 0);        \
    a1 = __builtin_amdgcn_mfma_f32_32x32x16_bf16(kh[1], qh_[1], a1, 0, 0, 0);        \
    a2 = __builtin_amdgcn_mfma_f32_32x32x16_bf16(kh[2], qh_[2], a2, 0, 0, 0);        \
    a3 = __builtin_amdgcn_mfma_f32_32x32x16_bf16(kh[3], qh_[3], a3, 0, 0, 0);        \
    a0 = __builtin_amdgcn_mfma_f32_32x32x16_bf16(kl[0], qh_[0], a0, 0, 0, 0);        \
    a1 = __builtin_amdgcn_mfma_f32_32x32x16_bf16(kl[1], qh_[1], a1, 0, 0, 0);        \
    a2 = __builtin_amdgcn_mfma_f32_32x32x16_bf16(kl[2], qh_[2], a2, 0, 0, 0);        \
    a3 = __builtin_amdgcn_mfma_f32_32x32x16_bf16(kl[3], qh_[3], a3, 0, 0, 0);        \
    a0 = __builtin_amdgcn_mfma_f32_32x32x16_bf16(kh[0], ql_[0], a0, 0, 0, 0);        \
    a1 = __builtin_amdgcn_mfma_f32_32x32x16_bf16(kh[1], ql_[1], a1, 0, 0, 0);        \
    a2 = __builtin_amdgcn_mfma_f32_32x32x16_bf16(kh[2], ql_[2], a2, 0, 0, 0);        \
    a3 = __builtin_amdgcn_mfma_f32_32x32x16_bf16(kh[3], ql_[3], a3, 0, 0, 0);        \
    _Pragma("unroll") for (int r = 0; r < 16; ++r)                                   \
        kacc[r] += fexp2(fmaf((a0[r] + a1[r]) + (a2[r] + a3[r]), EXP2C, lw_));       \
  }

  STAGE(0, 0);
  // fused combine: lg2w for this block's 512 q-rows (+ invs from x==0 blocks)
  for (int v = tid; v < 512; v += 256) {
    const int q = qc * 512 + v;
    float s = 0.f;
#pragma unroll
    for (int c = 0; c < 8; ++c) s += s_part[((size_t)(b * 8 + c) << 12) + q];
    lg2wl[v] = -__log2f(s);
    if (blockIdx.x == 0) invs[b * N_PIX + q] = 1.f / s;
  }
  __syncthreads();
  int bu = 0;
  for (int t = 0; t < 16; ++t) {
    if (t < 15) STAGE(bu ^ 1, t + 1);
    COMP(bu, t);
    __syncthreads();
    bu ^= 1;
  }
#undef STAGE
#undef COMP
#pragma unroll
  for (int r = 0; r < 16; ++r)
#pragma unroll
    for (int m = 1; m < 32; m <<= 1) kacc[r] += __shfl_xor(kacc[r], m);
  if (lr == 0) {
#pragma unroll
    for (int r = 0; r < 16; ++r) {
      const int row = (r & 3) + 8 * (r >> 2) + 4 * lh;
      cs_part[((size_t)(b * 8 + qc) << 12) + k0 + wv * 32 + row] = kacc[r];
    }
  }
}

// ---------------- top-128 per batch: deterministic 4-pass radix select ----------------
__global__ __launch_bounds__(256) void topk_kernel(const float* __restrict__ cs_part,
                                                   int* __restrict__ topk) {
  __shared__ unsigned keys[4096];
  __shared__ unsigned hist[256];
  __shared__ unsigned sbuf[256];
  __shared__ unsigned selB, selNeed;
  const int b = blockIdx.x, tid = threadIdx.x;
  for (int v = tid; v < 4096; v += 256) {
    float s = 0.f;
#pragma unroll
    for (int qc = 0; qc < 8; ++qc) s += cs_part[((size_t)(b * 8 + qc) << 12) + v];
    unsigned u = __float_as_uint(s);
    keys[v] = (u & 0x80000000u) ? ~u : (u | 0x80000000u);
  }
  unsigned need = 128, prefix = 0;
  __syncthreads();
  for (int d = 3; d >= 0; --d) {
    const int shift = d * 8;
    hist[tid] = 0;
    __syncthreads();
    for (int v = tid; v < 4096; v += 256) {
      const unsigned k = keys[v];
      if (d == 3 || (k >> (shift + 8)) == prefix)
        atomicAdd(&hist[(k >> shift) & 255], 1u);
    }
    __syncthreads();
    sbuf[tid] = hist[tid];
    __syncthreads();
    for (int off = 1; off < 256; off <<= 1) {
      const unsigned add = (tid + off < 256) ? sbuf[tid + off] : 0;
      __syncthreads();
      sbuf[tid] += add;
      __syncthreads();
    }
    const unsigned sufGe = sbuf[tid];
    const unsigned sufGt = (tid < 255) ? sbuf[tid + 1] : 0;
    if (sufGt < need && need <= sufGe) {
      selB = (unsigned)tid;
      selNeed = need - sufGt;
    }
    __syncthreads();
    prefix = (prefix << 8) | selB;
    need = selNeed;
    __syncthreads();
  }
  const unsigned T = prefix;
  unsigned gtc = 0, eqc = 0;
#pragma unroll
  for (int j = 0; j < 16; ++j) {
    const unsigned k = keys[tid * 16 + j];
    gtc += (k > T);
    eqc += (k == T);
  }
  sbuf[tid] = (gtc << 16) | eqc;
  __syncthreads();
  for (int off = 1; off < 256; off <<= 1) {
    const unsigned add = (tid >= off) ? sbuf[tid - off] : 0;
    __syncthreads();
    sbuf[tid] += add;
    __syncthreads();
  }
  const unsigned incl = sbuf[tid];
  const unsigned gBase = (incl >> 16) - gtc;
  const unsigned eBase = (incl & 0xffffu) - eqc;
  const unsigned nGt = sbuf[255] >> 16;
  unsigned g = 0, e = 0;
#pragma unroll
  for (int j = 0; j < 16; ++j) {
    const int idx = tid * 16 + j;
    const unsigned k = keys[idx];
    if (k > T) {
      topk[b * 128 + gBase + g] = idx;
      ++g;
    } else if (k == T) {
      if (eBase + e < need) topk[b * 128 + nGt + eBase + e] = idx;
      ++e;
    }
  }
}

// ---------------- masked attention output + fused final projection ----------------
// 32 q-rows per block (grid 128x4 = 512 blocks, LDS 69.9KB -> 2 blocks/CU).
__global__ __launch_bounds__(256) void attn_out_kernel(
    const unsigned short* __restrict__ Qhp, const unsigned short* __restrict__ Qlp,
    const unsigned short* __restrict__ Khp, const unsigned short* __restrict__ Klp,
    const float* __restrict__ Vm, const float* __restrict__ invs,
    const int* __restrict__ topkb, const float* __restrict__ wo,
    const float* __restrict__ bo, float* __restrict__ dout) {
  __shared__ float Qld[32 * 68], Kld[64 * 68], Vt[64 * 68], Pl[32 * 68], Wl[64 * 68];
  __shared__ int sidx[64];
  const int b = blockIdx.y, q0 = blockIdx.x * 32;
  const int tid = threadIdx.x, tx = tid & 15, ty = tid >> 4;
  const size_t base = (size_t)b * N_PIX;
  for (int v = tid; v < 512; v += 256) {
    int row = v >> 4, c4 = (v & 15) * 4;
    size_t off = (base + q0 + row) * 64 + c4;
    ushort4 h = *(const ushort4*)(Qhp + off);
    ushort4 lo = *(const ushort4*)(Qlp + off);
    float4 f;
    f.x = bf2f(h.x) + bf2f(lo.x);
    f.y = bf2f(h.y) + bf2f(lo.y);
    f.z = bf2f(h.z) + bf2f(lo.z);
    f.w = bf2f(h.w) + bf2f(lo.w);
    *(float4*)&Qld[swz(row, c4)] = f;
  }
  for (int v = tid; v < 1024; v += 256) {
    int row = v >> 4, c4 = (v & 15) * 4;
    *(float4*)&Wl[swz(row, c4)] = *(const float4*)(wo + row * 64 + c4);
  }
  float is[2];
#pragma unroll
  for (int i = 0; i < 2; ++i) is[i] = invs[base + q0 + ty * 2 + i];
  float acc[2][4];
#pragma unroll
  for (int i = 0; i < 2; ++i)
#pragma unroll
    for (int j = 0; j < 4; ++j) acc[i][j] = 0.f;
  for (int ch = 0; ch < 2; ++ch) {
    __syncthreads();
    if (tid < 64) sidx[tid] = topkb[b * 128 + ch * 64 + tid];
    __syncthreads();
    for (int v = tid; v < 1024; v += 256) {
      int row = v >> 4, c4 = (v & 15) * 4;
      size_t off = (base + sidx[row]) * 64 + c4;
      ushort4 h = *(const ushort4*)(Khp + off);
      ushort4 lo = *(const ushort4*)(Klp + off);
      float4 f;
      f.x = bf2f(h.x) + bf2f(lo.x);
      f.y = bf2f(h.y) + bf2f(lo.y);
      f.z = bf2f(h.z) + bf2f(lo.z);
      f.w = bf2f(h.w) + bf2f(lo.w);
      *(float4*)&Kld[swz(row, c4)] = f;
    }
    for (int v = tid; v < 4096; v += 256) {
      int row = v >> 6, c = v & 63;
      Vt[swz(c, row)] = Vm[(base + sidx[row]) * 64 + c];
    }
    __syncthreads();
    float z[2][4];
#pragma unroll
    for (int i = 0; i < 2; ++i)
#pragma unroll
      for (int j = 0; j < 4; ++j) z[i][j] = 0.f;
#pragma unroll
    for (int e4 = 0; e4 < 16; ++e4) {
      float4 qa[2], ka[4];
#pragma unroll
      for (int i = 0; i < 2; ++i) qa[i] = *(const float4*)&Qld[swz(ty * 2 + i, e4 * 4)];
#pragma unroll
      for (int j = 0; j < 4; ++j) ka[j] = *(const float4*)&Kld[swz(tx * 4 + j, e4 * 4)];
#pragma unroll
      for (int i = 0; i < 2; ++i)
#pragma unroll
        for (int j = 0; j < 4; ++j)
#pragma unroll
          for (int u = 0; u < 4; ++u)
            z[i][j] = fmaf(fget(qa[i], u), fget(ka[j], u), z[i][j]);
    }
#pragma unroll
    for (int i = 0; i < 2; ++i)
#pragma unroll
      for (int j = 0; j < 4; ++j)
        Pl[swz(ty * 2 + i, tx * 4 + j)] = __expf(z[i][j] * 0.125f) * is[i];
    __syncthreads();
#pragma unroll
    for (int k4 = 0; k4 < 16; ++k4) {
      float4 pr[2], vr[4];
#pragma unroll
      for (int i = 0; i < 2; ++i) pr[i] = *(const float4*)&Pl[swz(ty * 2 + i, k4 * 4)];
#pragma unroll
      for (int j = 0; j < 4; ++j) vr[j] = *(const float4*)&Vt[swz(tx * 4 + j, k4 * 4)];
#pragma unroll
      for (int i = 0; i < 2; ++i)
#pragma unroll
        for (int j = 0; j < 4; ++j)
#pragma unroll
          for (int u = 0; u < 4; ++u)
            acc[i][j] = fmaf(fget(pr[i], u), fget(vr[j], u), acc[i][j]);
    }
  }
  __syncthreads();
#pragma unroll
  for (int i = 0; i < 2; ++i)
#pragma unroll
    for (int j = 0; j < 4; ++j) Pl[swz(ty * 2 + i, tx * 4 + j)] = acc[i][j];
  __syncthreads();
  float yacc[2][4];
#pragma unroll
  for (int i = 0; i < 2; ++i)
#pragma unroll
    for (int j = 0; j < 4; ++j) yacc[i][j] = 0.f;
#pragma unroll
  for (int e4 = 0; e4 < 16; ++e4) {
    float4 a[2], wr[4];
#pragma unroll
    for (int i = 0; i < 2; ++i) a[i] = *(const float4*)&Pl[swz(ty * 2 + i, e4 * 4)];
#pragma unroll
    for (int u = 0; u < 4; ++u) wr[u] = *(const float4*)&Wl[swz(e4 * 4 + u, tx * 4)];
#pragma unroll
    for (int i = 0; i < 2; ++i)
#pragma unroll
      for (int j = 0; j < 4; ++j)
#pragma unroll
        for (int u = 0; u < 4; ++u)
          yacc[i][j] = fmaf(fget(a[i], u), fget(wr[u], j), yacc[i][j]);
  }
  __syncthreads();
#pragma unroll
  for (int i = 0; i < 2; ++i)
#pragma unroll
    for (int j = 0; j < 4; ++j)
      Qld[swz(ty * 2 + i, tx * 4 + j)] = yacc[i][j] + bo[tx * 4 + j];
  __syncthreads();
  for (int v = tid; v < 2048; v += 256) {
    int c = v >> 5, nl = v & 31;
    dout[((size_t)b * 64 + c) * 4096 + q0 + nl] = Qld[swz(nl, c)];
  }
}

extern "C" void kernel_launch(void* const* d_in, const int* in_sizes, int n_in,
                              void* d_out, int out_size, void* d_ws, size_t ws_size,
                              hipStream_t stream) {
  const float* x = (const float*)d_in[0];
  const float* w1 = (const float*)d_in[1];
  const float* b1 = (const float*)d_in[2];
  const float* w3 = (const float*)d_in[3];
  const float* b3 = (const float*)d_in[4];
  const float* w5 = (const float*)d_in[5];
  const float* b5 = (const float*)d_in[6];
  const float* wq = (const float*)d_in[7];
  const float* bq = (const float*)d_in[8];
  const float* wk = (const float*)d_in[9];
  const float* bk = (const float*)d_in[10];
  const float* wv = (const float*)d_in[11];
  const float* bv = (const float*)d_in[12];
  const float* wo = (const float*)d_in[13];
  const float* bo = (const float*)d_in[14];

  const size_t BN = (size_t)4 * N_PIX;  // 16384
  char* p = (char*)d_ws;
  auto carve = [&](size_t bytes) -> void* {
    void* r = (void*)p;
    p += (bytes + 255) & ~(size_t)255;
    return r;
  };
  unsigned short* Bfh = (unsigned short*)carve((size_t)25 * 12 * 2 * 512 * 2);
  unsigned short* Bfl = (unsigned short*)carve((size_t)25 * 12 * 2 * 512 * 2);
  float* beff = (float*)carve(192 * 4);
  unsigned short* Xth = (unsigned short*)carve((size_t)4 * 68 * 72 * 64 * 2);
  unsigned short* Xtl = (unsigned short*)carve((size_t)4 * 68 * 72 * 64 * 2);
  float* Vm = (float*)carve(BN * 64 * 4);
  unsigned short* Qhi = (unsigned short*)carve(BN * 64 * 2);
  unsigned short* Qlo = (unsigned short*)carve(BN * 64 * 2);
  unsigned short* Khi = (unsigned short*)carve(BN * 64 * 2);
  unsigned short* Klo = (unsigned short*)carve(BN * 64 * 2);
  float* s_part = (float*)carve((size_t)4 * 8 * 4096 * 4);
  float* invs = (float*)carve(BN * 4);
  float* cs_part = (float*)carve((size_t)4 * 8 * 4096 * 4);
  int* topkbuf = (int*)carve(512 * 4);

  prep_kernel<<<dim3(3, 26), 256, 0, stream>>>(w1, w3, w5, wq, wk, wv, b1, b3, b5,
                                               bq, bk, bv, Bfh, Bfl, beff);
  xpose_kernel<<<dim3(68, 4), 256, 0, stream>>>(x, Xth, Xtl);
  fused_qkv_kernel<<<dim3(64, 4, 3), 256, 0, stream>>>(Xth, Xtl, Bfh, Bfl, beff, Qhi,
                                                       Qlo, Khi, Klo, Vm);
  qk_s_kernel<<<dim3(32, 8, 4), 256, 0, stream>>>(Qhi, Qlo, Khi, Klo, s_part);
  colsum_kernel2<<<dim3(32, 8, 4), 256, 0, stream>>>(Qhi, Qlo, Khi, Klo, s_part,
                                                     invs, cs_part);
  topk_kernel<<<4, 256, 0, stream>>>(cs_part, topkbuf);
  attn_out_kernel<<<dim3(128, 4), 256, 0, stream>>>(Qhi, Qlo, Khi, Klo, Vm, invs,
                                                    topkbuf, wo, bo, (float*)d_out);
}

// Round 22
// 158.740 us; speedup vs baseline: 1.0863x; 1.0863x over previous
//
#include <hip/hip_runtime.h>
#include <math.h>

#define N_PIX 4096
#define CCH 64

typedef __attribute__((ext_vector_type(8))) short short8;
typedef __attribute__((ext_vector_type(4))) float f32x4;
typedef __attribute__((ext_vector_type(16))) float f32x16;

#define EXP2C 0.18033688f  // 0.125 * log2(e)

// LDS tiles are [rows][68] floats; XOR-swizzle the 4-float granule by (row>>2)&7
// so that 4-row-strided b128 reads spread across bank groups (else 8-way conflict).
__device__ __forceinline__ int swz(int row, int col) {
  return row * 68 + (col ^ (((row >> 2) & 7) << 2));
}

__device__ __forceinline__ float fget(const float4& v, int j) {
  return ((const float*)&v)[j];
}

__device__ __forceinline__ unsigned short f2bf(float f) {
  unsigned u = __float_as_uint(f);
  unsigned r = (u + 0x7fff + ((u >> 16) & 1)) >> 16;
  return (unsigned short)r;
}
__device__ __forceinline__ float bf2f(unsigned short h) {
  return __uint_as_float((unsigned)h << 16);
}

// raw-rate exp2 (single v_exp_f32); inputs here are bounded (|z|<~8, lg2w ~ -12)
__device__ __forceinline__ float fexp2(float x) {
#if __has_builtin(__builtin_amdgcn_exp2f)
  return __builtin_amdgcn_exp2f(x);
#else
  return exp2f(x);
#endif
}

// async global->LDS, 16B per lane. Builtin path: LDS dest = wave-uniform base +
// lane*16 (m104); GLOBAL SOURCE IS PER-LANE - caller must add lane offset.
__device__ __forceinline__ void gll16(const unsigned short* g, unsigned short* lbase,
                                      int lane) {
#if __has_builtin(__builtin_amdgcn_global_load_lds)
  (void)lane;
  __builtin_amdgcn_global_load_lds(
      (const __attribute__((address_space(1))) void*)g,
      (__attribute__((address_space(3))) void*)lbase, 16, 0, 0);
#else
  *(short8*)(lbase + lane * 8) = *(const short8*)g;
#endif
}

// ---------------- weight prep: fold conv weights into wq|wk|wv (+ beff slice) -------
// Grid (3, 26): t<25 -> Weff tap-GEMM; t==25 -> effective bias for this 'which'.
__global__ __launch_bounds__(256) void prep_kernel(
    const float* __restrict__ w1, const float* __restrict__ w3,
    const float* __restrict__ w5, const float* __restrict__ wq,
    const float* __restrict__ wk, const float* __restrict__ wv,
    const float* __restrict__ b1, const float* __restrict__ b3,
    const float* __restrict__ b5, const float* __restrict__ bq,
    const float* __restrict__ bk, const float* __restrict__ bv,
    unsigned short* __restrict__ Bfh, unsigned short* __restrict__ Bfl,
    float* __restrict__ beff) {
  __shared__ float At[64 * 68];  // A[i][o] = wconv[o,i,tap]
  __shared__ float Bt[64 * 68];  // B[o][em] = Wsel[rowbase+o][em]
  const int which = blockIdx.x, t = blockIdx.y;
  const float* Wsel = which == 0 ? wq : (which == 1 ? wk : wv);
  const int tid = threadIdx.x, tx = tid & 15, ty = tid >> 4;
  if (t == 25) {  // beff slice: beff[which*64+e] = bcat[e] + sum_row bconv*Wcat
    if (tid < 64) {
      const float* bsel = which == 0 ? bq : (which == 1 ? bk : bv);
      float s = bsel[tid];
      for (int row = 0; row < 192; ++row) {
        const float bc = row < 64 ? b1[row] : (row < 128 ? b3[row - 64] : b5[row - 128]);
        s += bc * Wsel[row * 64 + tid];
      }
      beff[which * 64 + tid] = s;
    }
    return;
  }
  const int ky = t / 5, kx = t % 5;
  const bool in3 = (ky >= 1 && ky <= 3 && kx >= 1 && kx <= 3);
  const bool c1 = (t == 12);
  const int t3 = (ky - 1) * 3 + (kx - 1);
  float acc[4][4];
#pragma unroll
  for (int i = 0; i < 4; ++i)
#pragma unroll
    for (int j = 0; j < 4; ++j) acc[i][j] = 0.f;
  const int npass = 1 + (in3 ? 1 : 0) + (c1 ? 1 : 0);
  for (int pass = 0; pass < npass; ++pass) {
    const int kind = pass == 0 ? 0 : (pass == 1 && in3 ? 1 : 2);
    const int rowbase = kind == 0 ? 128 : (kind == 1 ? 64 : 0);
    __syncthreads();
    for (int v = tid; v < 4096; v += 256) {
      const int i = v & 63, o = v >> 6;
      float a;
      if (kind == 0) a = w5[(size_t)(o * 64 + i) * 25 + t];
      else if (kind == 1) a = w3[(size_t)(o * 64 + i) * 9 + t3];
      else a = w1[o * 64 + i];
      At[swz(i, o)] = a;
    }
    for (int v = tid; v < 1024; v += 256) {
      const int row = v >> 4, c4 = (v & 15) * 4;
      *(float4*)&Bt[swz(row, c4)] = *(const float4*)(Wsel + (rowbase + row) * 64 + c4);
    }
    __syncthreads();
#pragma unroll
    for (int o4 = 0; o4 < 16; ++o4) {
      float4 a[4], b[4];
#pragma unroll
      for (int i = 0; i < 4; ++i) a[i] = *(const float4*)&At[swz(ty * 4 + i, o4 * 4)];
#pragma unroll
      for (int u = 0; u < 4; ++u) b[u] = *(const float4*)&Bt[swz(o4 * 4 + u, tx * 4)];
#pragma unroll
      for (int i = 0; i < 4; ++i)
#pragma unroll
        for (int j = 0; j < 4; ++j)
#pragma unroll
          for (int u = 0; u < 4; ++u)
            acc[i][j] = fmaf(fget(a[i], u), fget(b[u], j), acc[i][j]);
    }
  }
#pragma unroll
  for (int ii = 0; ii < 4; ++ii) {
    const int i = ty * 4 + ii;
    const int s = i >> 5, lg = (i >> 3) & 3, j = i & 7;
#pragma unroll
    for (int jj = 0; jj < 4; ++jj) {
      const int em = tx * 4 + jj;
      const int q = which * 4 + (em >> 4), lr = em & 15;
      const size_t off = ((size_t)(t * 12 + q) * 2 + s) * 512 + (lg * 16 + lr) * 8 + j;
      const float val = acc[ii][jj];
      const unsigned short h = f2bf(val);
      Bfh[off] = h;
      Bfl[off] = f2bf(val - bf2f(h));
    }
  }
}

// ---------------- x transpose: [b][c][y][x] fp32 -> Xt[b][68][72][64] bf16 hi/lo -----
__global__ __launch_bounds__(256) void xpose_kernel(const float* __restrict__ x,
                                                    unsigned short* __restrict__ Xth,
                                                    unsigned short* __restrict__ Xtl) {
  __shared__ float t[64][65];
  const int yp = blockIdx.x;  // 0..67
  const int b = blockIdx.y;
  const int tid = threadIdx.x;
  const size_t rowbase = ((size_t)b * 68 + yp) * 72 * 64;  // ushort index
  short8 z8 = {0, 0, 0, 0, 0, 0, 0, 0};
  if (yp < 2 || yp >= 66) {
    short8* ph = (short8*)(Xth + rowbase);
    short8* pl = (short8*)(Xtl + rowbase);
    for (int v = tid; v < 576; v += 256) {  // 72*64/8
      ph[v] = z8;
      pl[v] = z8;
    }
    return;
  }
  const int y = yp - 2;
  for (int it = 0; it < 16; ++it) {
    const int v = it * 256 + tid;
    const int c = v >> 6, xx = v & 63;
    t[xx][c] = x[(((size_t)b * 64 + c) * 64 + y) * 64 + xx];
  }
  for (int s = tid; s < 64; s += 256) {
    const int col = s >> 3;
    const int xp = col < 2 ? col : col + 64;
    const size_t o = rowbase + (size_t)xp * 64 + (s & 7) * 8;
    *(short8*)(Xth + o) = z8;
    *(short8*)(Xtl + o) = z8;
  }
  __syncthreads();
  for (int it = 0; it < 16; ++it) {
    const int v = it * 256 + tid;
    const int xx = v >> 6, c = v & 63;
    const float val = t[xx][c];
    const unsigned short h = f2bf(val);
    const unsigned short lo = f2bf(val - bf2f(h));
    const int xp = xx + 2;
    const size_t idx = rowbase + (size_t)xp * 64 + (c ^ ((xp & 7) << 3));
    Xth[idx] = h;
    Xtl[idx] = lo;
  }
}

// ---------------- fused im2col GEMM: Xt -> Q(hi/lo), K(hi/lo), V ----------------
// Grid (64 tiles, 4 b, 3 z): block 256 = 4 waves. Wave wv owns quadrant
// qd = z*4+wv x ALL 64 pixels; 768 blocks -> 3 blocks/CU hides B latency.
__global__ __launch_bounds__(256) void fused_qkv_kernel(
    const unsigned short* __restrict__ Xth, const unsigned short* __restrict__ Xtl,
    const unsigned short* __restrict__ Bfh, const unsigned short* __restrict__ Bfl,
    const float* __restrict__ beff, unsigned short* __restrict__ Qhi,
    unsigned short* __restrict__ Qlo, unsigned short* __restrict__ Khi,
    unsigned short* __restrict__ Klo, float* __restrict__ Vm) {
  __shared__ unsigned short Lh[192 * 64];  // [12 rows][16 px][64 ch] = 24KB
  __shared__ unsigned short Ll[192 * 64];
  const int b = blockIdx.y, sb = blockIdx.x;
  const int y0 = (sb >> 3) * 8, x0 = (sb & 7) * 8;
  const int tid = threadIdx.x, wv = tid >> 6, l = tid & 63;
  const int lr = l & 15, lg = l >> 4;
  const int qd = blockIdx.z * 4 + wv;  // this wave's output quadrant (0..11)
#pragma unroll
  for (int rr = 0; rr < 3; ++rr) {
    const int py = wv * 3 + rr;
    const size_t src = (((size_t)b * 68 + y0 + py) * 72 + x0) * 64 + (size_t)l * 8;
    gll16(Xth + src, &Lh[py * 1024], l);
    gll16(Xth + src + 512, &Lh[py * 1024 + 512], l);
    gll16(Xtl + src, &Ll[py * 1024], l);
    gll16(Xtl + src + 512, &Ll[py * 1024 + 512], l);
  }
  __syncthreads();
  f32x4 acc[4];
#pragma unroll
  for (int pg = 0; pg < 4; ++pg) acc[pg] = (f32x4){0.f, 0.f, 0.f, 0.f};
  for (int ky = 0; ky < 5; ++ky) {
    for (int kx = 0; kx < 5; ++kx) {
      const int t = ky * 5 + kx;
      const size_t f = ((size_t)(t * 12 + qd)) * 2;
      const short8 bh0 = *(const short8*)&Bfh[f * 512 + l * 8];
      const short8 bh1 = *(const short8*)&Bfh[(f + 1) * 512 + l * 8];
      const short8 bl0 = *(const short8*)&Bfl[f * 512 + l * 8];
      const short8 bl1 = *(const short8*)&Bfl[(f + 1) * 512 + l * 8];
#pragma unroll
      for (int pg = 0; pg < 4; ++pg) {
        const int p = pg * 16 + lr;
        const int prt = ((p >> 3) + ky) * 16 + (p & 7) + kx;
        const int rb = prt * 64, sw = (prt & 7) << 3;
        const short8 ah0 = *(const short8*)&Lh[rb + ((lg * 8) ^ sw)];
        const short8 ah1 = *(const short8*)&Lh[rb + ((32 + lg * 8) ^ sw)];
        const short8 al0 = *(const short8*)&Ll[rb + ((lg * 8) ^ sw)];
        const short8 al1 = *(const short8*)&Ll[rb + ((32 + lg * 8) ^ sw)];
        acc[pg] = __builtin_amdgcn_mfma_f32_16x16x32_bf16(ah0, bh0, acc[pg], 0, 0, 0);
        acc[pg] = __builtin_amdgcn_mfma_f32_16x16x32_bf16(ah1, bh1, acc[pg], 0, 0, 0);
        acc[pg] = __builtin_amdgcn_mfma_f32_16x16x32_bf16(al0, bh0, acc[pg], 0, 0, 0);
        acc[pg] = __builtin_amdgcn_mfma_f32_16x16x32_bf16(al1, bh1, acc[pg], 0, 0, 0);
        acc[pg] = __builtin_amdgcn_mfma_f32_16x16x32_bf16(ah0, bl0, acc[pg], 0, 0, 0);
        acc[pg] = __builtin_amdgcn_mfma_f32_16x16x32_bf16(ah1, bl1, acc[pg], 0, 0, 0);
      }
    }
  }
  const size_t base = (size_t)b * N_PIX;
  {
    const int e = qd * 16 + lr;
    const int which = e >> 6, em = e & 63;
    const float be = beff[e];
#pragma unroll
    for (int pg = 0; pg < 4; ++pg) {
#pragma unroll
      for (int r = 0; r < 4; ++r) {
        const int pp = pg * 16 + lg * 4 + r;
        const int n = (y0 + (pp >> 3)) * 64 + x0 + (pp & 7);
        const float val = acc[pg][r] + be;
        const size_t off = (base + n) * 64 + em;
        if (which == 2) {
          Vm[off] = val;
        } else {
          const unsigned short h = f2bf(val);
          const unsigned short lo = f2bf(val - bf2f(h));
          if (which == 0) {
            Qhi[off] = h;
            Qlo[off] = lo;
          } else {
            Khi[off] = h;
            Klo[off] = lo;
          }
        }
      }
    }
  }
}

// ---------------- sweep 1: row sums of exp(z), LDS-staged K (depth-1), 2-chain MFMA --
__global__ __launch_bounds__(256) void qk_s_kernel(
    const unsigned short* __restrict__ Qhi, const unsigned short* __restrict__ Qlo,
    const unsigned short* __restrict__ Khi, const unsigned short* __restrict__ Klo,
    float* __restrict__ s_part) {
  __shared__ unsigned short Kst[2][2][2048];  // [buf][hi/lo][32*64]
  const int b = blockIdx.z, kc = blockIdx.y, q0 = blockIdx.x * 128;
  const int tid = threadIdx.x, wv = tid >> 6, l = tid & 63;
  const int lr = l & 31, lh = l >> 5;
  const size_t base = (size_t)b * N_PIX;
  const size_t qoff = (base + q0 + wv * 32 + lr) * 64 + lh * 8;
  short8 qh[4], ql[4];
#pragma unroll
  for (int f = 0; f < 4; ++f) {
    qh[f] = *(const short8*)(Qhi + qoff + f * 16);
    ql[f] = *(const short8*)(Qlo + qoff + f * 16);
  }
  const int srow = tid >> 3;
  const int gcu = ((tid & 7) * 8) ^ ((srow & 7) << 3);
  const unsigned short* Ksh = Khi + (base + kc * 512 + srow) * 64 + gcu;
  const unsigned short* Ksl = Klo + (base + kc * 512 + srow) * 64 + gcu;
  float racc[16];
#pragma unroll
  for (int r = 0; r < 16; ++r) racc[r] = 0.f;

#define STAGE(bb, t)                                   \
  {                                                    \
    const size_t go_ = (size_t)(t) * 2048;             \
    gll16(Ksh + go_, &Kst[bb][0][wv * 512], l);        \
    gll16(Ksl + go_, &Kst[bb][1][wv * 512], l);        \
  }
// two independent accumulator chains (f=0,1 vs f=2,3) to break MFMA serial latency
#define COMP(bb)                                                                     \
  {                                                                                  \
    short8 kh_[4], kl_[4];                                                           \
    const int rb_ = lr * 64, sw_ = (lr & 7) << 3;                                    \
    _Pragma("unroll") for (int f = 0; f < 4; ++f) {                                  \
      const int c_ = rb_ + ((lh * 8 + f * 16) ^ sw_);                                \
      kh_[f] = *(const short8*)&Kst[bb][0][c_];                                      \
      kl_[f] = *(const short8*)&Kst[bb][1][c_];                                      \
    }                                                                                \
    f32x16 a0, a1;                                                                   \
    _Pragma("unroll") for (int r = 0; r < 16; ++r) { a0[r] = 0.f; a1[r] = 0.f; }     \
    a0 = __builtin_amdgcn_mfma_f32_32x32x16_bf16(qh[0], kh_[0], a0, 0, 0, 0);        \
    a1 = __builtin_amdgcn_mfma_f32_32x32x16_bf16(qh[2], kh_[2], a1, 0, 0, 0);        \
    a0 = __builtin_amdgcn_mfma_f32_32x32x16_bf16(qh[1], kh_[1], a0, 0, 0, 0);        \
    a1 = __builtin_amdgcn_mfma_f32_32x32x16_bf16(qh[3], kh_[3], a1, 0, 0, 0);        \
    a0 = __builtin_amdgcn_mfma_f32_32x32x16_bf16(ql[0], kh_[0], a0, 0, 0, 0);        \
    a1 = __builtin_amdgcn_mfma_f32_32x32x16_bf16(ql[2], kh_[2], a1, 0, 0, 0);        \
    a0 = __builtin_amdgcn_mfma_f32_32x32x16_bf16(ql[1], kh_[1], a0, 0, 0, 0);        \
    a1 = __builtin_amdgcn_mfma_f32_32x32x16_bf16(ql[3], kh_[3], a1, 0, 0, 0);        \
    a0 = __builtin_amdgcn_mfma_f32_32x32x16_bf16(qh[0], kl_[0], a0, 0, 0, 0);        \
    a1 = __builtin_amdgcn_mfma_f32_32x32x16_bf16(qh[2], kl_[2], a1, 0, 0, 0);        \
    a0 = __builtin_amdgcn_mfma_f32_32x32x16_bf16(qh[1], kl_[1], a0, 0, 0, 0);        \
    a1 = __builtin_amdgcn_mfma_f32_32x32x16_bf16(qh[3], kl_[3], a1, 0, 0, 0);        \
    _Pragma("unroll") for (int r = 0; r < 16; ++r)                                   \
        racc[r] += fexp2((a0[r] + a1[r]) * EXP2C);                                   \
  }

  STAGE(0, 0);
  __syncthreads();
  int bu = 0;
  for (int t = 0; t < 16; ++t) {
    if (t < 15) STAGE(bu ^ 1, t + 1);
    COMP(bu);
    __syncthreads();
    bu ^= 1;
  }
#undef STAGE
#undef COMP
#pragma unroll
  for (int r = 0; r < 16; ++r)
#pragma unroll
    for (int m = 1; m < 32; m <<= 1) racc[r] += __shfl_xor(racc[r], m);
  if (lr == 0) {
#pragma unroll
    for (int r = 0; r < 16; ++r) {
      const int row = (r & 3) + 8 * (r >> 2) + 4 * lh;
      s_part[((size_t)(b * 8 + kc) << 12) + q0 + wv * 32 + row] = racc[r];
    }
  }
}

// ---------------- sweep 2: weighted col sums + fused combine (grid 32x8x4) ---------
// Prologue: each block computes lg2w for its 512 q-rows from s_part (redundant,
// ~2KB of loads); blockIdx.x==0 blocks also write invs for attn_out.
__global__ __launch_bounds__(256) void colsum_kernel2(
    const unsigned short* __restrict__ Qhi, const unsigned short* __restrict__ Qlo,
    const unsigned short* __restrict__ Khi, const unsigned short* __restrict__ Klo,
    const float* __restrict__ s_part, float* __restrict__ invs,
    float* __restrict__ cs_part) {
  __shared__ unsigned short Qst[2][2][2048];
  __shared__ float lg2wl[512];
  const int b = blockIdx.z, qc = blockIdx.y, k0 = blockIdx.x * 128;
  const int tid = threadIdx.x, wv = tid >> 6, l = tid & 63;
  const int lr = l & 31, lh = l >> 5;
  const size_t base = (size_t)b * N_PIX;
  const size_t koff = (base + k0 + wv * 32 + lr) * 64 + lh * 8;
  short8 kh[4], kl[4];
#pragma unroll
  for (int f = 0; f < 4; ++f) {
    kh[f] = *(const short8*)(Khi + koff + f * 16);
    kl[f] = *(const short8*)(Klo + koff + f * 16);
  }
  const int srow = tid >> 3;
  const int gcu = ((tid & 7) * 8) ^ ((srow & 7) << 3);
  const unsigned short* Qsh = Qhi + (base + qc * 512 + srow) * 64 + gcu;
  const unsigned short* Qsl = Qlo + (base + qc * 512 + srow) * 64 + gcu;
  float kacc[16];
#pragma unroll
  for (int r = 0; r < 16; ++r) kacc[r] = 0.f;

#define STAGE(bb, t)                                   \
  {                                                    \
    const size_t go_ = (size_t)(t) * 2048;             \
    gll16(Qsh + go_, &Qst[bb][0][wv * 512], l);        \
    gll16(Qsl + go_, &Qst[bb][1][wv * 512], l);        \
  }
#define COMP(bb, t_)                                                                 \
  {                                                                                  \
    const float lw_ = lg2wl[(t_) * 32 + lr];                                         \
    short8 qh_[4], ql_[4];                                                           \
    const int rb_ = lr * 64, sw_ = (lr & 7) << 3;                                    \
    _Pragma("unroll") for (int f = 0; f < 4; ++f) {                                  \
      const int c_ = rb_ + ((lh * 8 + f * 16) ^ sw_);                                \
      qh_[f] = *(const short8*)&Qst[bb][0][c_];                                      \
      ql_[f] = *(const short8*)&Qst[bb][1][c_];                                      \
    }                                                                                \
    f32x16 a0, a1;                                                                   \
    _Pragma("unroll") for (int r = 0; r < 16; ++r) { a0[r] = 0.f; a1[r] = 0.f; }     \
    a0 = __builtin_amdgcn_mfma_f32_32x32x16_bf16(kh[0], qh_[0], a0, 0, 0, 0);        \
    a1 = __builtin_amdgcn_mfma_f32_32x32x16_bf16(kh[2], qh_[2], a1, 0, 0, 0);        \
    a0 = __builtin_amdgcn_mfma_f32_32x32x16_bf16(kh[1], qh_[1], a0, 0, 0, 0);        \
    a1 = __builtin_amdgcn_mfma_f32_32x32x16_bf16(kh[3], qh_[3], a1, 0, 0, 0);        \
    a0 = __builtin_amdgcn_mfma_f32_32x32x16_bf16(kl[0], qh_[0], a0, 0, 0, 0);        \
    a1 = __builtin_amdgcn_mfma_f32_32x32x16_bf16(kl[2], qh_[2], a1, 0, 0, 0);        \
    a0 = __builtin_amdgcn_mfma_f32_32x32x16_bf16(kl[1], qh_[1], a0, 0, 0, 0);        \
    a1 = __builtin_amdgcn_mfma_f32_32x32x16_bf16(kl[3], qh_[3], a1, 0, 0, 0);        \
    a0 = __builtin_amdgcn_mfma_f32_32x32x16_bf16(kh[0], ql_[0], a0, 0, 0, 0);        \
    a1 = __builtin_amdgcn_mfma_f32_32x32x16_bf16(kh[2], ql_[2], a1, 0, 0, 0);        \
    a0 = __builtin_amdgcn_mfma_f32_32x32x16_bf16(kh[1], ql_[1], a0, 0, 0, 0);        \
    a1 = __builtin_amdgcn_mfma_f32_32x32x16_bf16(kh[3], ql_[3], a1, 0, 0, 0);        \
    _Pragma("unroll") for (int r = 0; r < 16; ++r)                                   \
        kacc[r] += fexp2(fmaf(a0[r] + a1[r], EXP2C, lw_));                           \
  }

  STAGE(0, 0);
  // fused combine: lg2w for this block's 512 q-rows (+ invs from x==0 blocks)
  for (int v = tid; v < 512; v += 256) {
    const int q = qc * 512 + v;
    float s = 0.f;
#pragma unroll
    for (int c = 0; c < 8; ++c) s += s_part[((size_t)(b * 8 + c) << 12) + q];
    lg2wl[v] = -__log2f(s);
    if (blockIdx.x == 0) invs[b * N_PIX + q] = 1.f / s;
  }
  __syncthreads();
  int bu = 0;
  for (int t = 0; t < 16; ++t) {
    if (t < 15) STAGE(bu ^ 1, t + 1);
    COMP(bu, t);
    __syncthreads();
    bu ^= 1;
  }
#undef STAGE
#undef COMP
#pragma unroll
  for (int r = 0; r < 16; ++r)
#pragma unroll
    for (int m = 1; m < 32; m <<= 1) kacc[r] += __shfl_xor(kacc[r], m);
  if (lr == 0) {
#pragma unroll
    for (int r = 0; r < 16; ++r) {
      const int row = (r & 3) + 8 * (r >> 2) + 4 * lh;
      cs_part[((size_t)(b * 8 + qc) << 12) + k0 + wv * 32 + row] = kacc[r];
    }
  }
}

// ---------------- top-128 per batch: deterministic 4-pass radix select ----------------
__global__ __launch_bounds__(256) void topk_kernel(const float* __restrict__ cs_part,
                                                   int* __restrict__ topk) {
  __shared__ unsigned keys[4096];
  __shared__ unsigned hist[256];
  __shared__ unsigned sbuf[256];
  __shared__ unsigned selB, selNeed;
  const int b = blockIdx.x, tid = threadIdx.x;
  for (int v = tid; v < 4096; v += 256) {
    float s = 0.f;
#pragma unroll
    for (int qc = 0; qc < 8; ++qc) s += cs_part[((size_t)(b * 8 + qc) << 12) + v];
    unsigned u = __float_as_uint(s);
    keys[v] = (u & 0x80000000u) ? ~u : (u | 0x80000000u);
  }
  unsigned need = 128, prefix = 0;
  __syncthreads();
  for (int d = 3; d >= 0; --d) {
    const int shift = d * 8;
    hist[tid] = 0;
    __syncthreads();
    for (int v = tid; v < 4096; v += 256) {
      const unsigned k = keys[v];
      if (d == 3 || (k >> (shift + 8)) == prefix)
        atomicAdd(&hist[(k >> shift) & 255], 1u);
    }
    __syncthreads();
    sbuf[tid] = hist[tid];
    __syncthreads();
    for (int off = 1; off < 256; off <<= 1) {
      const unsigned add = (tid + off < 256) ? sbuf[tid + off] : 0;
      __syncthreads();
      sbuf[tid] += add;
      __syncthreads();
    }
    const unsigned sufGe = sbuf[tid];
    const unsigned sufGt = (tid < 255) ? sbuf[tid + 1] : 0;
    if (sufGt < need && need <= sufGe) {
      selB = (unsigned)tid;
      selNeed = need - sufGt;
    }
    __syncthreads();
    prefix = (prefix << 8) | selB;
    need = selNeed;
    __syncthreads();
  }
  const unsigned T = prefix;
  unsigned gtc = 0, eqc = 0;
#pragma unroll
  for (int j = 0; j < 16; ++j) {
    const unsigned k = keys[tid * 16 + j];
    gtc += (k > T);
    eqc += (k == T);
  }
  sbuf[tid] = (gtc << 16) | eqc;
  __syncthreads();
  for (int off = 1; off < 256; off <<= 1) {
    const unsigned add = (tid >= off) ? sbuf[tid - off] : 0;
    __syncthreads();
    sbuf[tid] += add;
    __syncthreads();
  }
  const unsigned incl = sbuf[tid];
  const unsigned gBase = (incl >> 16) - gtc;
  const unsigned eBase = (incl & 0xffffu) - eqc;
  const unsigned nGt = sbuf[255] >> 16;
  unsigned g = 0, e = 0;
#pragma unroll
  for (int j = 0; j < 16; ++j) {
    const int idx = tid * 16 + j;
    const unsigned k = keys[idx];
    if (k > T) {
      topk[b * 128 + gBase + g] = idx;
      ++g;
    } else if (k == T) {
      if (eBase + e < need) topk[b * 128 + nGt + eBase + e] = idx;
      ++e;
    }
  }
}

// ---------------- masked attention output + fused final projection ----------------
// 32 q-rows per block (grid 128x4 = 512 blocks, LDS 69.9KB -> 2 blocks/CU).
__global__ __launch_bounds__(256) void attn_out_kernel(
    const unsigned short* __restrict__ Qhp, const unsigned short* __restrict__ Qlp,
    const unsigned short* __restrict__ Khp, const unsigned short* __restrict__ Klp,
    const float* __restrict__ Vm, const float* __restrict__ invs,
    const int* __restrict__ topkb, const float* __restrict__ wo,
    const float* __restrict__ bo, float* __restrict__ dout) {
  __shared__ float Qld[32 * 68], Kld[64 * 68], Vt[64 * 68], Pl[32 * 68], Wl[64 * 68];
  __shared__ int sidx[64];
  const int b = blockIdx.y, q0 = blockIdx.x * 32;
  const int tid = threadIdx.x, tx = tid & 15, ty = tid >> 4;
  const size_t base = (size_t)b * N_PIX;
  for (int v = tid; v < 512; v += 256) {
    int row = v >> 4, c4 = (v & 15) * 4;
    size_t off = (base + q0 + row) * 64 + c4;
    ushort4 h = *(const ushort4*)(Qhp + off);
    ushort4 lo = *(const ushort4*)(Qlp + off);
    float4 f;
    f.x = bf2f(h.x) + bf2f(lo.x);
    f.y = bf2f(h.y) + bf2f(lo.y);
    f.z = bf2f(h.z) + bf2f(lo.z);
    f.w = bf2f(h.w) + bf2f(lo.w);
    *(float4*)&Qld[swz(row, c4)] = f;
  }
  for (int v = tid; v < 1024; v += 256) {
    int row = v >> 4, c4 = (v & 15) * 4;
    *(float4*)&Wl[swz(row, c4)] = *(const float4*)(wo + row * 64 + c4);
  }
  float is[2];
#pragma unroll
  for (int i = 0; i < 2; ++i) is[i] = invs[base + q0 + ty * 2 + i];
  float acc[2][4];
#pragma unroll
  for (int i = 0; i < 2; ++i)
#pragma unroll
    for (int j = 0; j < 4; ++j) acc[i][j] = 0.f;
  for (int ch = 0; ch < 2; ++ch) {
    __syncthreads();
    if (tid < 64) sidx[tid] = topkb[b * 128 + ch * 64 + tid];
    __syncthreads();
    for (int v = tid; v < 1024; v += 256) {
      int row = v >> 4, c4 = (v & 15) * 4;
      size_t off = (base + sidx[row]) * 64 + c4;
      ushort4 h = *(const ushort4*)(Khp + off);
      ushort4 lo = *(const ushort4*)(Klp + off);
      float4 f;
      f.x = bf2f(h.x) + bf2f(lo.x);
      f.y = bf2f(h.y) + bf2f(lo.y);
      f.z = bf2f(h.z) + bf2f(lo.z);
      f.w = bf2f(h.w) + bf2f(lo.w);
      *(float4*)&Kld[swz(row, c4)] = f;
    }
    for (int v = tid; v < 4096; v += 256) {
      int row = v >> 6, c = v & 63;
      Vt[swz(c, row)] = Vm[(base + sidx[row]) * 64 + c];
    }
    __syncthreads();
    float z[2][4];
#pragma unroll
    for (int i = 0; i < 2; ++i)
#pragma unroll
      for (int j = 0; j < 4; ++j) z[i][j] = 0.f;
#pragma unroll
    for (int e4 = 0; e4 < 16; ++e4) {
      float4 qa[2], ka[4];
#pragma unroll
      for (int i = 0; i < 2; ++i) qa[i] = *(const float4*)&Qld[swz(ty * 2 + i, e4 * 4)];
#pragma unroll
      for (int j = 0; j < 4; ++j) ka[j] = *(const float4*)&Kld[swz(tx * 4 + j, e4 * 4)];
#pragma unroll
      for (int i = 0; i < 2; ++i)
#pragma unroll
        for (int j = 0; j < 4; ++j)
#pragma unroll
          for (int u = 0; u < 4; ++u)
            z[i][j] = fmaf(fget(qa[i], u), fget(ka[j], u), z[i][j]);
    }
#pragma unroll
    for (int i = 0; i < 2; ++i)
#pragma unroll
      for (int j = 0; j < 4; ++j)
        Pl[swz(ty * 2 + i, tx * 4 + j)] = __expf(z[i][j] * 0.125f) * is[i];
    __syncthreads();
#pragma unroll
    for (int k4 = 0; k4 < 16; ++k4) {
      float4 pr[2], vr[4];
#pragma unroll
      for (int i = 0; i < 2; ++i) pr[i] = *(const float4*)&Pl[swz(ty * 2 + i, k4 * 4)];
#pragma unroll
      for (int j = 0; j < 4; ++j) vr[j] = *(const float4*)&Vt[swz(tx * 4 + j, k4 * 4)];
#pragma unroll
      for (int i = 0; i < 2; ++i)
#pragma unroll
        for (int j = 0; j < 4; ++j)
#pragma unroll
          for (int u = 0; u < 4; ++u)
            acc[i][j] = fmaf(fget(pr[i], u), fget(vr[j], u), acc[i][j]);
    }
  }
  __syncthreads();
#pragma unroll
  for (int i = 0; i < 2; ++i)
#pragma unroll
    for (int j = 0; j < 4; ++j) Pl[swz(ty * 2 + i, tx * 4 + j)] = acc[i][j];
  __syncthreads();
  float yacc[2][4];
#pragma unroll
  for (int i = 0; i < 2; ++i)
#pragma unroll
    for (int j = 0; j < 4; ++j) yacc[i][j] = 0.f;
#pragma unroll
  for (int e4 = 0; e4 < 16; ++e4) {
    float4 a[2], wr[4];
#pragma unroll
    for (int i = 0; i < 2; ++i) a[i] = *(const float4*)&Pl[swz(ty * 2 + i, e4 * 4)];
#pragma unroll
    for (int u = 0; u < 4; ++u) wr[u] = *(const float4*)&Wl[swz(e4 * 4 + u, tx * 4)];
#pragma unroll
    for (int i = 0; i < 2; ++i)
#pragma unroll
      for (int j = 0; j < 4; ++j)
#pragma unroll
        for (int u = 0; u < 4; ++u)
          yacc[i][j] = fmaf(fget(a[i], u), fget(wr[u], j), yacc[i][j]);
  }
  __syncthreads();
#pragma unroll
  for (int i = 0; i < 2; ++i)
#pragma unroll
    for (int j = 0; j < 4; ++j)
      Qld[swz(ty * 2 + i, tx * 4 + j)] = yacc[i][j] + bo[tx * 4 + j];
  __syncthreads();
  for (int v = tid; v < 2048; v += 256) {
    int c = v >> 5, nl = v & 31;
    dout[((size_t)b * 64 + c) * 4096 + q0 + nl] = Qld[swz(nl, c)];
  }
}

extern "C" void kernel_launch(void* const* d_in, const int* in_sizes, int n_in,
                              void* d_out, int out_size, void* d_ws, size_t ws_size,
                              hipStream_t stream) {
  const float* x = (const float*)d_in[0];
  const float* w1 = (const float*)d_in[1];
  const float* b1 = (const float*)d_in[2];
  const float* w3 = (const float*)d_in[3];
  const float* b3 = (const float*)d_in[4];
  const float* w5 = (const float*)d_in[5];
  const float* b5 = (const float*)d_in[6];
  const float* wq = (const float*)d_in[7];
  const float* bq = (const float*)d_in[8];
  const float* wk = (const float*)d_in[9];
  const float* bk = (const float*)d_in[10];
  const float* wv = (const float*)d_in[11];
  const float* bv = (const float*)d_in[12];
  const float* wo = (const float*)d_in[13];
  const float* bo = (const float*)d_in[14];

  const size_t BN = (size_t)4 * N_PIX;  // 16384
  char* p = (char*)d_ws;
  auto carve = [&](size_t bytes) -> void* {
    void* r = (void*)p;
    p += (bytes + 255) & ~(size_t)255;
    return r;
  };
  unsigned short* Bfh = (unsigned short*)carve((size_t)25 * 12 * 2 * 512 * 2);
  unsigned short* Bfl = (unsigned short*)carve((size_t)25 * 12 * 2 * 512 * 2);
  float* beff = (float*)carve(192 * 4);
  unsigned short* Xth = (unsigned short*)carve((size_t)4 * 68 * 72 * 64 * 2);
  unsigned short* Xtl = (unsigned short*)carve((size_t)4 * 68 * 72 * 64 * 2);
  float* Vm = (float*)carve(BN * 64 * 4);
  unsigned short* Qhi = (unsigned short*)carve(BN * 64 * 2);
  unsigned short* Qlo = (unsigned short*)carve(BN * 64 * 2);
  unsigned short* Khi = (unsigned short*)carve(BN * 64 * 2);
  unsigned short* Klo = (unsigned short*)carve(BN * 64 * 2);
  float* s_part = (float*)carve((size_t)4 * 8 * 4096 * 4);
  float* invs = (float*)carve(BN * 4);
  float* cs_part = (float*)carve((size_t)4 * 8 * 4096 * 4);
  int* topkbuf = (int*)carve(512 * 4);

  prep_kernel<<<dim3(3, 26), 256, 0, stream>>>(w1, w3, w5, wq, wk, wv, b1, b3, b5,
                                               bq, bk, bv, Bfh, Bfl, beff);
  xpose_kernel<<<dim3(68, 4), 256, 0, stream>>>(x, Xth, Xtl);
  fused_qkv_kernel<<<dim3(64, 4, 3), 256, 0, stream>>>(Xth, Xtl, Bfh, Bfl, beff, Qhi,
                                                       Qlo, Khi, Klo, Vm);
  qk_s_kernel<<<dim3(32, 8, 4), 256, 0, stream>>>(Qhi, Qlo, Khi, Klo, s_part);
  colsum_kernel2<<<dim3(32, 8, 4), 256, 0, stream>>>(Qhi, Qlo, Khi, Klo, s_part,
                                                     invs, cs_part);
  topk_kernel<<<4, 256, 0, stream>>>(cs_part, topkbuf);
  attn_out_kernel<<<dim3(128, 4), 256, 0, stream>>>(Qhi, Qlo, Khi, Klo, Vm, invs,
                                                    topkbuf, wo, bo, (float*)d_out);
}

// Round 23
// 156.596 us; speedup vs baseline: 1.1012x; 1.0137x over previous
//
#include <hip/hip_runtime.h>
#include <math.h>

#define N_PIX 4096
#define CCH 64

typedef __attribute__((ext_vector_type(8))) short short8;
typedef __attribute__((ext_vector_type(4))) float f32x4;
typedef __attribute__((ext_vector_type(16))) float f32x16;

#define EXP2C 0.18033688f  // 0.125 * log2(e)

// LDS tiles are [rows][68] floats; XOR-swizzle the 4-float granule by (row>>2)&7
// so that 4-row-strided b128 reads spread across bank groups (else 8-way conflict).
__device__ __forceinline__ int swz(int row, int col) {
  return row * 68 + (col ^ (((row >> 2) & 7) << 2));
}

__device__ __forceinline__ float fget(const float4& v, int j) {
  return ((const float*)&v)[j];
}

__device__ __forceinline__ unsigned short f2bf(float f) {
  unsigned u = __float_as_uint(f);
  unsigned r = (u + 0x7fff + ((u >> 16) & 1)) >> 16;
  return (unsigned short)r;
}
__device__ __forceinline__ float bf2f(unsigned short h) {
  return __uint_as_float((unsigned)h << 16);
}

// raw-rate exp2 (single v_exp_f32); inputs here are bounded (|z|<~8, lg2w ~ -12)
__device__ __forceinline__ float fexp2(float x) {
#if __has_builtin(__builtin_amdgcn_exp2f)
  return __builtin_amdgcn_exp2f(x);
#else
  return exp2f(x);
#endif
}

// async global->LDS, 16B per lane. Builtin path: LDS dest = wave-uniform base +
// lane*16 (m104); GLOBAL SOURCE IS PER-LANE - caller must add lane offset.
__device__ __forceinline__ void gll16(const unsigned short* g, unsigned short* lbase,
                                      int lane) {
#if __has_builtin(__builtin_amdgcn_global_load_lds)
  (void)lane;
  __builtin_amdgcn_global_load_lds(
      (const __attribute__((address_space(1))) void*)g,
      (__attribute__((address_space(3))) void*)lbase, 16, 0, 0);
#else
  *(short8*)(lbase + lane * 8) = *(const short8*)g;
#endif
}

// ---------------- setup: xpose (blocks 0..271) + weight prep (blocks 272..349) ------
// Independent workloads merged into one dispatch; prep's latency-bound blocks
// co-schedule with xpose's bandwidth phase.
__global__ __launch_bounds__(256) void setup_kernel(
    const float* __restrict__ x, const float* __restrict__ w1,
    const float* __restrict__ w3, const float* __restrict__ w5,
    const float* __restrict__ wq, const float* __restrict__ wk,
    const float* __restrict__ wv, const float* __restrict__ b1,
    const float* __restrict__ b3, const float* __restrict__ b5,
    const float* __restrict__ bq, const float* __restrict__ bk,
    const float* __restrict__ bv, unsigned short* __restrict__ Xth,
    unsigned short* __restrict__ Xtl, unsigned short* __restrict__ Bfh,
    unsigned short* __restrict__ Bfl, float* __restrict__ beff) {
  __shared__ char smem[2 * 64 * 68 * 4];  // union: prep At+Bt (34.8KB) / xpose t (16.6KB)
  const int tid = threadIdx.x;
  if (blockIdx.x < 272) {
    // ----- xpose slice: [b][c][y][x] fp32 -> Xt[b][68][72][64] bf16 hi/lo -----
    float(*t)[65] = (float(*)[65])smem;
    const int yp = blockIdx.x % 68;
    const int b = blockIdx.x / 68;
    const size_t rowbase = ((size_t)b * 68 + yp) * 72 * 64;  // ushort index
    short8 z8 = {0, 0, 0, 0, 0, 0, 0, 0};
    if (yp < 2 || yp >= 66) {
      short8* ph = (short8*)(Xth + rowbase);
      short8* pl = (short8*)(Xtl + rowbase);
      for (int v = tid; v < 576; v += 256) {  // 72*64/8
        ph[v] = z8;
        pl[v] = z8;
      }
      return;
    }
    const int y = yp - 2;
    for (int it = 0; it < 16; ++it) {
      const int v = it * 256 + tid;
      const int c = v >> 6, xx = v & 63;
      t[xx][c] = x[(((size_t)b * 64 + c) * 64 + y) * 64 + xx];
    }
    for (int s = tid; s < 64; s += 256) {
      const int col = s >> 3;
      const int xp = col < 2 ? col : col + 64;
      const size_t o = rowbase + (size_t)xp * 64 + (s & 7) * 8;
      *(short8*)(Xth + o) = z8;
      *(short8*)(Xtl + o) = z8;
    }
    __syncthreads();
    for (int it = 0; it < 16; ++it) {
      const int v = it * 256 + tid;
      const int xx = v >> 6, c = v & 63;
      const float val = t[xx][c];
      const unsigned short h = f2bf(val);
      const unsigned short lo = f2bf(val - bf2f(h));
      const int xp = xx + 2;
      const size_t idx = rowbase + (size_t)xp * 64 + (c ^ ((xp & 7) << 3));
      Xth[idx] = h;
      Xtl[idx] = lo;
    }
    return;
  }
  // ----- prep slice: fold conv weights into wq|wk|wv (+ beff at t==25) -----
  float* At = (float*)smem;                 // A[i][o] = wconv[o,i,tap]
  float* Bt = (float*)(smem + 64 * 68 * 4); // B[o][em] = Wsel[rowbase+o][em]
  const int idx78 = blockIdx.x - 272;
  const int which = idx78 % 3, t = idx78 / 3;
  const float* Wsel = which == 0 ? wq : (which == 1 ? wk : wv);
  const int tx = tid & 15, ty = tid >> 4;
  if (t == 25) {  // beff slice: beff[which*64+e] = bcat[e] + sum_row bconv*Wcat
    if (tid < 64) {
      const float* bsel = which == 0 ? bq : (which == 1 ? bk : bv);
      float s = bsel[tid];
      for (int row = 0; row < 192; ++row) {
        const float bc = row < 64 ? b1[row] : (row < 128 ? b3[row - 64] : b5[row - 128]);
        s += bc * Wsel[row * 64 + tid];
      }
      beff[which * 64 + tid] = s;
    }
    return;
  }
  const int ky = t / 5, kx = t % 5;
  const bool in3 = (ky >= 1 && ky <= 3 && kx >= 1 && kx <= 3);
  const bool c1 = (t == 12);
  const int t3 = (ky - 1) * 3 + (kx - 1);
  float acc[4][4];
#pragma unroll
  for (int i = 0; i < 4; ++i)
#pragma unroll
    for (int j = 0; j < 4; ++j) acc[i][j] = 0.f;
  const int npass = 1 + (in3 ? 1 : 0) + (c1 ? 1 : 0);
  for (int pass = 0; pass < npass; ++pass) {
    const int kind = pass == 0 ? 0 : (pass == 1 && in3 ? 1 : 2);
    const int rowbase = kind == 0 ? 128 : (kind == 1 ? 64 : 0);
    __syncthreads();
    for (int v = tid; v < 4096; v += 256) {
      const int i = v & 63, o = v >> 6;
      float a;
      if (kind == 0) a = w5[(size_t)(o * 64 + i) * 25 + t];
      else if (kind == 1) a = w3[(size_t)(o * 64 + i) * 9 + t3];
      else a = w1[o * 64 + i];
      At[swz(i, o)] = a;
    }
    for (int v = tid; v < 1024; v += 256) {
      const int row = v >> 4, c4 = (v & 15) * 4;
      *(float4*)&Bt[swz(row, c4)] = *(const float4*)(Wsel + (rowbase + row) * 64 + c4);
    }
    __syncthreads();
#pragma unroll
    for (int o4 = 0; o4 < 16; ++o4) {
      float4 a[4], b[4];
#pragma unroll
      for (int i = 0; i < 4; ++i) a[i] = *(const float4*)&At[swz(ty * 4 + i, o4 * 4)];
#pragma unroll
      for (int u = 0; u < 4; ++u) b[u] = *(const float4*)&Bt[swz(o4 * 4 + u, tx * 4)];
#pragma unroll
      for (int i = 0; i < 4; ++i)
#pragma unroll
        for (int j = 0; j < 4; ++j)
#pragma unroll
          for (int u = 0; u < 4; ++u)
            acc[i][j] = fmaf(fget(a[i], u), fget(b[u], j), acc[i][j]);
    }
  }
#pragma unroll
  for (int ii = 0; ii < 4; ++ii) {
    const int i = ty * 4 + ii;
    const int s = i >> 5, lg = (i >> 3) & 3, j = i & 7;
#pragma unroll
    for (int jj = 0; jj < 4; ++jj) {
      const int em = tx * 4 + jj;
      const int q = which * 4 + (em >> 4), lr = em & 15;
      const size_t off = ((size_t)(t * 12 + q) * 2 + s) * 512 + (lg * 16 + lr) * 8 + j;
      const float val = acc[ii][jj];
      const unsigned short h = f2bf(val);
      Bfh[off] = h;
      Bfl[off] = f2bf(val - bf2f(h));
    }
  }
}

// ---------------- fused im2col GEMM: Xt -> Q(hi/lo), K(hi/lo), V ----------------
// Grid (64 tiles, 4 b, 3 z): block 256 = 4 waves. Wave wv owns quadrant
// qd = z*4+wv x ALL 64 pixels; 768 blocks -> 3 blocks/CU hides B latency.
__global__ __launch_bounds__(256) void fused_qkv_kernel(
    const unsigned short* __restrict__ Xth, const unsigned short* __restrict__ Xtl,
    const unsigned short* __restrict__ Bfh, const unsigned short* __restrict__ Bfl,
    const float* __restrict__ beff, unsigned short* __restrict__ Qhi,
    unsigned short* __restrict__ Qlo, unsigned short* __restrict__ Khi,
    unsigned short* __restrict__ Klo, float* __restrict__ Vm) {
  __shared__ unsigned short Lh[192 * 64];  // [12 rows][16 px][64 ch] = 24KB
  __shared__ unsigned short Ll[192 * 64];
  const int b = blockIdx.y, sb = blockIdx.x;
  const int y0 = (sb >> 3) * 8, x0 = (sb & 7) * 8;
  const int tid = threadIdx.x, wv = tid >> 6, l = tid & 63;
  const int lr = l & 15, lg = l >> 4;
  const int qd = blockIdx.z * 4 + wv;  // this wave's output quadrant (0..11)
#pragma unroll
  for (int rr = 0; rr < 3; ++rr) {
    const int py = wv * 3 + rr;
    const size_t src = (((size_t)b * 68 + y0 + py) * 72 + x0) * 64 + (size_t)l * 8;
    gll16(Xth + src, &Lh[py * 1024], l);
    gll16(Xth + src + 512, &Lh[py * 1024 + 512], l);
    gll16(Xtl + src, &Ll[py * 1024], l);
    gll16(Xtl + src + 512, &Ll[py * 1024 + 512], l);
  }
  __syncthreads();
  f32x4 acc[4];
#pragma unroll
  for (int pg = 0; pg < 4; ++pg) acc[pg] = (f32x4){0.f, 0.f, 0.f, 0.f};
  for (int ky = 0; ky < 5; ++ky) {
    for (int kx = 0; kx < 5; ++kx) {
      const int t = ky * 5 + kx;
      const size_t f = ((size_t)(t * 12 + qd)) * 2;
      const short8 bh0 = *(const short8*)&Bfh[f * 512 + l * 8];
      const short8 bh1 = *(const short8*)&Bfh[(f + 1) * 512 + l * 8];
      const short8 bl0 = *(const short8*)&Bfl[f * 512 + l * 8];
      const short8 bl1 = *(const short8*)&Bfl[(f + 1) * 512 + l * 8];
#pragma unroll
      for (int pg = 0; pg < 4; ++pg) {
        const int p = pg * 16 + lr;
        const int prt = ((p >> 3) + ky) * 16 + (p & 7) + kx;
        const int rb = prt * 64, sw = (prt & 7) << 3;
        const short8 ah0 = *(const short8*)&Lh[rb + ((lg * 8) ^ sw)];
        const short8 ah1 = *(const short8*)&Lh[rb + ((32 + lg * 8) ^ sw)];
        const short8 al0 = *(const short8*)&Ll[rb + ((lg * 8) ^ sw)];
        const short8 al1 = *(const short8*)&Ll[rb + ((32 + lg * 8) ^ sw)];
        acc[pg] = __builtin_amdgcn_mfma_f32_16x16x32_bf16(ah0, bh0, acc[pg], 0, 0, 0);
        acc[pg] = __builtin_amdgcn_mfma_f32_16x16x32_bf16(ah1, bh1, acc[pg], 0, 0, 0);
        acc[pg] = __builtin_amdgcn_mfma_f32_16x16x32_bf16(al0, bh0, acc[pg], 0, 0, 0);
        acc[pg] = __builtin_amdgcn_mfma_f32_16x16x32_bf16(al1, bh1, acc[pg], 0, 0, 0);
        acc[pg] = __builtin_amdgcn_mfma_f32_16x16x32_bf16(ah0, bl0, acc[pg], 0, 0, 0);
        acc[pg] = __builtin_amdgcn_mfma_f32_16x16x32_bf16(ah1, bl1, acc[pg], 0, 0, 0);
      }
    }
  }
  const size_t base = (size_t)b * N_PIX;
  {
    const int e = qd * 16 + lr;
    const int which = e >> 6, em = e & 63;
    const float be = beff[e];
#pragma unroll
    for (int pg = 0; pg < 4; ++pg) {
#pragma unroll
      for (int r = 0; r < 4; ++r) {
        const int pp = pg * 16 + lg * 4 + r;
        const int n = (y0 + (pp >> 3)) * 64 + x0 + (pp & 7);
        const float val = acc[pg][r] + be;
        const size_t off = (base + n) * 64 + em;
        if (which == 2) {
          Vm[off] = val;
        } else {
          const unsigned short h = f2bf(val);
          const unsigned short lo = f2bf(val - bf2f(h));
          if (which == 0) {
            Qhi[off] = h;
            Qlo[off] = lo;
          } else {
            Khi[off] = h;
            Klo[off] = lo;
          }
        }
      }
    }
  }
}

// ---------------- sweep 1: row sums of exp(z), LDS-staged K (depth-1), 2-chain MFMA --
__global__ __launch_bounds__(256) void qk_s_kernel(
    const unsigned short* __restrict__ Qhi, const unsigned short* __restrict__ Qlo,
    const unsigned short* __restrict__ Khi, const unsigned short* __restrict__ Klo,
    float* __restrict__ s_part) {
  __shared__ unsigned short Kst[2][2][2048];  // [buf][hi/lo][32*64]
  const int b = blockIdx.z, kc = blockIdx.y, q0 = blockIdx.x * 128;
  const int tid = threadIdx.x, wv = tid >> 6, l = tid & 63;
  const int lr = l & 31, lh = l >> 5;
  const size_t base = (size_t)b * N_PIX;
  const size_t qoff = (base + q0 + wv * 32 + lr) * 64 + lh * 8;
  short8 qh[4], ql[4];
#pragma unroll
  for (int f = 0; f < 4; ++f) {
    qh[f] = *(const short8*)(Qhi + qoff + f * 16);
    ql[f] = *(const short8*)(Qlo + qoff + f * 16);
  }
  const int srow = tid >> 3;
  const int gcu = ((tid & 7) * 8) ^ ((srow & 7) << 3);
  const unsigned short* Ksh = Khi + (base + kc * 512 + srow) * 64 + gcu;
  const unsigned short* Ksl = Klo + (base + kc * 512 + srow) * 64 + gcu;
  float racc[16];
#pragma unroll
  for (int r = 0; r < 16; ++r) racc[r] = 0.f;

#define STAGE(bb, t)                                   \
  {                                                    \
    const size_t go_ = (size_t)(t) * 2048;             \
    gll16(Ksh + go_, &Kst[bb][0][wv * 512], l);        \
    gll16(Ksl + go_, &Kst[bb][1][wv * 512], l);        \
  }
// two independent accumulator chains (f=0,1 vs f=2,3) to break MFMA serial latency
#define COMP(bb)                                                                     \
  {                                                                                  \
    short8 kh_[4], kl_[4];                                                           \
    const int rb_ = lr * 64, sw_ = (lr & 7) << 3;                                    \
    _Pragma("unroll") for (int f = 0; f < 4; ++f) {                                  \
      const int c_ = rb_ + ((lh * 8 + f * 16) ^ sw_);                                \
      kh_[f] = *(const short8*)&Kst[bb][0][c_];                                      \
      kl_[f] = *(const short8*)&Kst[bb][1][c_];                                      \
    }                                                                                \
    f32x16 a0, a1;                                                                   \
    _Pragma("unroll") for (int r = 0; r < 16; ++r) { a0[r] = 0.f; a1[r] = 0.f; }     \
    a0 = __builtin_amdgcn_mfma_f32_32x32x16_bf16(qh[0], kh_[0], a0, 0, 0, 0);        \
    a1 = __builtin_amdgcn_mfma_f32_32x32x16_bf16(qh[2], kh_[2], a1, 0, 0, 0);        \
    a0 = __builtin_amdgcn_mfma_f32_32x32x16_bf16(qh[1], kh_[1], a0, 0, 0, 0);        \
    a1 = __builtin_amdgcn_mfma_f32_32x32x16_bf16(qh[3], kh_[3], a1, 0, 0, 0);        \
    a0 = __builtin_amdgcn_mfma_f32_32x32x16_bf16(ql[0], kh_[0], a0, 0, 0, 0);        \
    a1 = __builtin_amdgcn_mfma_f32_32x32x16_bf16(ql[2], kh_[2], a1, 0, 0, 0);        \
    a0 = __builtin_amdgcn_mfma_f32_32x32x16_bf16(ql[1], kh_[1], a0, 0, 0, 0);        \
    a1 = __builtin_amdgcn_mfma_f32_32x32x16_bf16(ql[3], kh_[3], a1, 0, 0, 0);        \
    a0 = __builtin_amdgcn_mfma_f32_32x32x16_bf16(qh[0], kl_[0], a0, 0, 0, 0);        \
    a1 = __builtin_amdgcn_mfma_f32_32x32x16_bf16(qh[2], kl_[2], a1, 0, 0, 0);        \
    a0 = __builtin_amdgcn_mfma_f32_32x32x16_bf16(qh[1], kl_[1], a0, 0, 0, 0);        \
    a1 = __builtin_amdgcn_mfma_f32_32x32x16_bf16(qh[3], kl_[3], a1, 0, 0, 0);        \
    _Pragma("unroll") for (int r = 0; r < 16; ++r)                                   \
        racc[r] += fexp2((a0[r] + a1[r]) * EXP2C);                                   \
  }

  STAGE(0, 0);
  __syncthreads();
  int bu = 0;
  for (int t = 0; t < 16; ++t) {
    if (t < 15) STAGE(bu ^ 1, t + 1);
    COMP(bu);
    __syncthreads();
    bu ^= 1;
  }
#undef STAGE
#undef COMP
#pragma unroll
  for (int r = 0; r < 16; ++r)
#pragma unroll
    for (int m = 1; m < 32; m <<= 1) racc[r] += __shfl_xor(racc[r], m);
  if (lr == 0) {
#pragma unroll
    for (int r = 0; r < 16; ++r) {
      const int row = (r & 3) + 8 * (r >> 2) + 4 * lh;
      s_part[((size_t)(b * 8 + kc) << 12) + q0 + wv * 32 + row] = racc[r];
    }
  }
}

// ---------------- sweep 2: weighted col sums + fused combine (grid 32x8x4) ---------
// Prologue: each block computes lg2w for its 512 q-rows from s_part (redundant,
// ~2KB of loads); blockIdx.x==0 blocks also write invs for attn_out.
__global__ __launch_bounds__(256) void colsum_kernel2(
    const unsigned short* __restrict__ Qhi, const unsigned short* __restrict__ Qlo,
    const unsigned short* __restrict__ Khi, const unsigned short* __restrict__ Klo,
    const float* __restrict__ s_part, float* __restrict__ invs,
    float* __restrict__ cs_part) {
  __shared__ unsigned short Qst[2][2][2048];
  __shared__ float lg2wl[512];
  const int b = blockIdx.z, qc = blockIdx.y, k0 = blockIdx.x * 128;
  const int tid = threadIdx.x, wv = tid >> 6, l = tid & 63;
  const int lr = l & 31, lh = l >> 5;
  const size_t base = (size_t)b * N_PIX;
  const size_t koff = (base + k0 + wv * 32 + lr) * 64 + lh * 8;
  short8 kh[4], kl[4];
#pragma unroll
  for (int f = 0; f < 4; ++f) {
    kh[f] = *(const short8*)(Khi + koff + f * 16);
    kl[f] = *(const short8*)(Klo + koff + f * 16);
  }
  const int srow = tid >> 3;
  const int gcu = ((tid & 7) * 8) ^ ((srow & 7) << 3);
  const unsigned short* Qsh = Qhi + (base + qc * 512 + srow) * 64 + gcu;
  const unsigned short* Qsl = Qlo + (base + qc * 512 + srow) * 64 + gcu;
  float kacc[16];
#pragma unroll
  for (int r = 0; r < 16; ++r) kacc[r] = 0.f;

#define STAGE(bb, t)                                   \
  {                                                    \
    const size_t go_ = (size_t)(t) * 2048;             \
    gll16(Qsh + go_, &Qst[bb][0][wv * 512], l);        \
    gll16(Qsl + go_, &Qst[bb][1][wv * 512], l);        \
  }
#define COMP(bb, t_)                                                                 \
  {                                                                                  \
    const float lw_ = lg2wl[(t_) * 32 + lr];                                         \
    short8 qh_[4], ql_[4];                                                           \
    const int rb_ = lr * 64, sw_ = (lr & 7) << 3;                                    \
    _Pragma("unroll") for (int f = 0; f < 4; ++f) {                                  \
      const int c_ = rb_ + ((lh * 8 + f * 16) ^ sw_);                                \
      qh_[f] = *(const short8*)&Qst[bb][0][c_];                                      \
      ql_[f] = *(const short8*)&Qst[bb][1][c_];                                      \
    }                                                                                \
    f32x16 a0, a1;                                                                   \
    _Pragma("unroll") for (int r = 0; r < 16; ++r) { a0[r] = 0.f; a1[r] = 0.f; }     \
    a0 = __builtin_amdgcn_mfma_f32_32x32x16_bf16(kh[0], qh_[0], a0, 0, 0, 0);        \
    a1 = __builtin_amdgcn_mfma_f32_32x32x16_bf16(kh[2], qh_[2], a1, 0, 0, 0);        \
    a0 = __builtin_amdgcn_mfma_f32_32x32x16_bf16(kh[1], qh_[1], a0, 0, 0, 0);        \
    a1 = __builtin_amdgcn_mfma_f32_32x32x16_bf16(kh[3], qh_[3], a1, 0, 0, 0);        \
    a0 = __builtin_amdgcn_mfma_f32_32x32x16_bf16(kl[0], qh_[0], a0, 0, 0, 0);        \
    a1 = __builtin_amdgcn_mfma_f32_32x32x16_bf16(kl[2], qh_[2], a1, 0, 0, 0);        \
    a0 = __builtin_amdgcn_mfma_f32_32x32x16_bf16(kl[1], qh_[1], a0, 0, 0, 0);        \
    a1 = __builtin_amdgcn_mfma_f32_32x32x16_bf16(kl[3], qh_[3], a1, 0, 0, 0);        \
    a0 = __builtin_amdgcn_mfma_f32_32x32x16_bf16(kh[0], ql_[0], a0, 0, 0, 0);        \
    a1 = __builtin_amdgcn_mfma_f32_32x32x16_bf16(kh[2], ql_[2], a1, 0, 0, 0);        \
    a0 = __builtin_amdgcn_mfma_f32_32x32x16_bf16(kh[1], ql_[1], a0, 0, 0, 0);        \
    a1 = __builtin_amdgcn_mfma_f32_32x32x16_bf16(kh[3], ql_[3], a1, 0, 0, 0);        \
    _Pragma("unroll") for (int r = 0; r < 16; ++r)                                   \
        kacc[r] += fexp2(fmaf(a0[r] + a1[r], EXP2C, lw_));                           \
  }

  STAGE(0, 0);
  // fused combine: lg2w for this block's 512 q-rows (+ invs from x==0 blocks)
  for (int v = tid; v < 512; v += 256) {
    const int q = qc * 512 + v;
    float s = 0.f;
#pragma unroll
    for (int c = 0; c < 8; ++c) s += s_part[((size_t)(b * 8 + c) << 12) + q];
    lg2wl[v] = -__log2f(s);
    if (blockIdx.x == 0) invs[b * N_PIX + q] = 1.f / s;
  }
  __syncthreads();
  int bu = 0;
  for (int t = 0; t < 16; ++t) {
    if (t < 15) STAGE(bu ^ 1, t + 1);
    COMP(bu, t);
    __syncthreads();
    bu ^= 1;
  }
#undef STAGE
#undef COMP
#pragma unroll
  for (int r = 0; r < 16; ++r)
#pragma unroll
    for (int m = 1; m < 32; m <<= 1) kacc[r] += __shfl_xor(kacc[r], m);
  if (lr == 0) {
#pragma unroll
    for (int r = 0; r < 16; ++r) {
      const int row = (r & 3) + 8 * (r >> 2) + 4 * lh;
      cs_part[((size_t)(b * 8 + qc) << 12) + k0 + wv * 32 + row] = kacc[r];
    }
  }
}

// ---------------- top-128 per batch: deterministic 4-pass radix select ----------------
__global__ __launch_bounds__(256) void topk_kernel(const float* __restrict__ cs_part,
                                                   int* __restrict__ topk) {
  __shared__ unsigned keys[4096];
  __shared__ unsigned hist[256];
  __shared__ unsigned sbuf[256];
  __shared__ unsigned selB, selNeed;
  const int b = blockIdx.x, tid = threadIdx.x;
  for (int v = tid; v < 4096; v += 256) {
    float s = 0.f;
#pragma unroll
    for (int qc = 0; qc < 8; ++qc) s += cs_part[((size_t)(b * 8 + qc) << 12) + v];
    unsigned u = __float_as_uint(s);
    keys[v] = (u & 0x80000000u) ? ~u : (u | 0x80000000u);
  }
  unsigned need = 128, prefix = 0;
  __syncthreads();
  for (int d = 3; d >= 0; --d) {
    const int shift = d * 8;
    hist[tid] = 0;
    __syncthreads();
    for (int v = tid; v < 4096; v += 256) {
      const unsigned k = keys[v];
      if (d == 3 || (k >> (shift + 8)) == prefix)
        atomicAdd(&hist[(k >> shift) & 255], 1u);
    }
    __syncthreads();
    sbuf[tid] = hist[tid];
    __syncthreads();
    for (int off = 1; off < 256; off <<= 1) {
      const unsigned add = (tid + off < 256) ? sbuf[tid + off] : 0;
      __syncthreads();
      sbuf[tid] += add;
      __syncthreads();
    }
    const unsigned sufGe = sbuf[tid];
    const unsigned sufGt = (tid < 255) ? sbuf[tid + 1] : 0;
    if (sufGt < need && need <= sufGe) {
      selB = (unsigned)tid;
      selNeed = need - sufGt;
    }
    __syncthreads();
    prefix = (prefix << 8) | selB;
    need = selNeed;
    __syncthreads();
  }
  const unsigned T = prefix;
  unsigned gtc = 0, eqc = 0;
#pragma unroll
  for (int j = 0; j < 16; ++j) {
    const unsigned k = keys[tid * 16 + j];
    gtc += (k > T);
    eqc += (k == T);
  }
  sbuf[tid] = (gtc << 16) | eqc;
  __syncthreads();
  for (int off = 1; off < 256; off <<= 1) {
    const unsigned add = (tid >= off) ? sbuf[tid - off] : 0;
    __syncthreads();
    sbuf[tid] += add;
    __syncthreads();
  }
  const unsigned incl = sbuf[tid];
  const unsigned gBase = (incl >> 16) - gtc;
  const unsigned eBase = (incl & 0xffffu) - eqc;
  const unsigned nGt = sbuf[255] >> 16;
  unsigned g = 0, e = 0;
#pragma unroll
  for (int j = 0; j < 16; ++j) {
    const int idx = tid * 16 + j;
    const unsigned k = keys[idx];
    if (k > T) {
      topk[b * 128 + gBase + g] = idx;
      ++g;
    } else if (k == T) {
      if (eBase + e < need) topk[b * 128 + nGt + eBase + e] = idx;
      ++e;
    }
  }
}

// ---------------- masked attention output + fused final projection ----------------
// 32 q-rows per block (grid 128x4 = 512 blocks, LDS 69.9KB -> 2 blocks/CU).
__global__ __launch_bounds__(256) void attn_out_kernel(
    const unsigned short* __restrict__ Qhp, const unsigned short* __restrict__ Qlp,
    const unsigned short* __restrict__ Khp, const unsigned short* __restrict__ Klp,
    const float* __restrict__ Vm, const float* __restrict__ invs,
    const int* __restrict__ topkb, const float* __restrict__ wo,
    const float* __restrict__ bo, float* __restrict__ dout) {
  __shared__ float Qld[32 * 68], Kld[64 * 68], Vt[64 * 68], Pl[32 * 68], Wl[64 * 68];
  __shared__ int sidx[64];
  const int b = blockIdx.y, q0 = blockIdx.x * 32;
  const int tid = threadIdx.x, tx = tid & 15, ty = tid >> 4;
  const size_t base = (size_t)b * N_PIX;
  for (int v = tid; v < 512; v += 256) {
    int row = v >> 4, c4 = (v & 15) * 4;
    size_t off = (base + q0 + row) * 64 + c4;
    ushort4 h = *(const ushort4*)(Qhp + off);
    ushort4 lo = *(const ushort4*)(Qlp + off);
    float4 f;
    f.x = bf2f(h.x) + bf2f(lo.x);
    f.y = bf2f(h.y) + bf2f(lo.y);
    f.z = bf2f(h.z) + bf2f(lo.z);
    f.w = bf2f(h.w) + bf2f(lo.w);
    *(float4*)&Qld[swz(row, c4)] = f;
  }
  for (int v = tid; v < 1024; v += 256) {
    int row = v >> 4, c4 = (v & 15) * 4;
    *(float4*)&Wl[swz(row, c4)] = *(const float4*)(wo + row * 64 + c4);
  }
  float is[2];
#pragma unroll
  for (int i = 0; i < 2; ++i) is[i] = invs[base + q0 + ty * 2 + i];
  float acc[2][4];
#pragma unroll
  for (int i = 0; i < 2; ++i)
#pragma unroll
    for (int j = 0; j < 4; ++j) acc[i][j] = 0.f;
  for (int ch = 0; ch < 2; ++ch) {
    __syncthreads();
    if (tid < 64) sidx[tid] = topkb[b * 128 + ch * 64 + tid];
    __syncthreads();
    for (int v = tid; v < 1024; v += 256) {
      int row = v >> 4, c4 = (v & 15) * 4;
      size_t off = (base + sidx[row]) * 64 + c4;
      ushort4 h = *(const ushort4*)(Khp + off);
      ushort4 lo = *(const ushort4*)(Klp + off);
      float4 f;
      f.x = bf2f(h.x) + bf2f(lo.x);
      f.y = bf2f(h.y) + bf2f(lo.y);
      f.z = bf2f(h.z) + bf2f(lo.z);
      f.w = bf2f(h.w) + bf2f(lo.w);
      *(float4*)&Kld[swz(row, c4)] = f;
    }
    for (int v = tid; v < 4096; v += 256) {
      int row = v >> 6, c = v & 63;
      Vt[swz(c, row)] = Vm[(base + sidx[row]) * 64 + c];
    }
    __syncthreads();
    float z[2][4];
#pragma unroll
    for (int i = 0; i < 2; ++i)
#pragma unroll
      for (int j = 0; j < 4; ++j) z[i][j] = 0.f;
#pragma unroll
    for (int e4 = 0; e4 < 16; ++e4) {
      float4 qa[2], ka[4];
#pragma unroll
      for (int i = 0; i < 2; ++i) qa[i] = *(const float4*)&Qld[swz(ty * 2 + i, e4 * 4)];
#pragma unroll
      for (int j = 0; j < 4; ++j) ka[j] = *(const float4*)&Kld[swz(tx * 4 + j, e4 * 4)];
#pragma unroll
      for (int i = 0; i < 2; ++i)
#pragma unroll
        for (int j = 0; j < 4; ++j)
#pragma unroll
          for (int u = 0; u < 4; ++u)
            z[i][j] = fmaf(fget(qa[i], u), fget(ka[j], u), z[i][j]);
    }
#pragma unroll
    for (int i = 0; i < 2; ++i)
#pragma unroll
      for (int j = 0; j < 4; ++j)
        Pl[swz(ty * 2 + i, tx * 4 + j)] = __expf(z[i][j] * 0.125f) * is[i];
    __syncthreads();
#pragma unroll
    for (int k4 = 0; k4 < 16; ++k4) {
      float4 pr[2], vr[4];
#pragma unroll
      for (int i = 0; i < 2; ++i) pr[i] = *(const float4*)&Pl[swz(ty * 2 + i, k4 * 4)];
#pragma unroll
      for (int j = 0; j < 4; ++j) vr[j] = *(const float4*)&Vt[swz(tx * 4 + j, k4 * 4)];
#pragma unroll
      for (int i = 0; i < 2; ++i)
#pragma unroll
        for (int j = 0; j < 4; ++j)
#pragma unroll
          for (int u = 0; u < 4; ++u)
            acc[i][j] = fmaf(fget(pr[i], u), fget(vr[j], u), acc[i][j]);
    }
  }
  __syncthreads();
#pragma unroll
  for (int i = 0; i < 2; ++i)
#pragma unroll
    for (int j = 0; j < 4; ++j) Pl[swz(ty * 2 + i, tx * 4 + j)] = acc[i][j];
  __syncthreads();
  float yacc[2][4];
#pragma unroll
  for (int i = 0; i < 2; ++i)
#pragma unroll
    for (int j = 0; j < 4; ++j) yacc[i][j] = 0.f;
#pragma unroll
  for (int e4 = 0; e4 < 16; ++e4) {
    float4 a[2], wr[4];
#pragma unroll
    for (int i = 0; i < 2; ++i) a[i] = *(const float4*)&Pl[swz(ty * 2 + i, e4 * 4)];
#pragma unroll
    for (int u = 0; u < 4; ++u) wr[u] = *(const float4*)&Wl[swz(e4 * 4 + u, tx * 4)];
#pragma unroll
    for (int i = 0; i < 2; ++i)
#pragma unroll
      for (int j = 0; j < 4; ++j)
#pragma unroll
        for (int u = 0; u < 4; ++u)
          yacc[i][j] = fmaf(fget(a[i], u), fget(wr[u], j), yacc[i][j]);
  }
  __syncthreads();
#pragma unroll
  for (int i = 0; i < 2; ++i)
#pragma unroll
    for (int j = 0; j < 4; ++j)
      Qld[swz(ty * 2 + i, tx * 4 + j)] = yacc[i][j] + bo[tx * 4 + j];
  __syncthreads();
  for (int v = tid; v < 2048; v += 256) {
    int c = v >> 5, nl = v & 31;
    dout[((size_t)b * 64 + c) * 4096 + q0 + nl] = Qld[swz(nl, c)];
  }
}

extern "C" void kernel_launch(void* const* d_in, const int* in_sizes, int n_in,
                              void* d_out, int out_size, void* d_ws, size_t ws_size,
                              hipStream_t stream) {
  const float* x = (const float*)d_in[0];
  const float* w1 = (const float*)d_in[1];
  const float* b1 = (const float*)d_in[2];
  const float* w3 = (const float*)d_in[3];
  const float* b3 = (const float*)d_in[4];
  const float* w5 = (const float*)d_in[5];
  const float* b5 = (const float*)d_in[6];
  const float* wq = (const float*)d_in[7];
  const float* bq = (const float*)d_in[8];
  const float* wk = (const float*)d_in[9];
  const float* bk = (const float*)d_in[10];
  const float* wv = (const float*)d_in[11];
  const float* bv = (const float*)d_in[12];
  const float* wo = (const float*)d_in[13];
  const float* bo = (const float*)d_in[14];

  const size_t BN = (size_t)4 * N_PIX;  // 16384
  char* p = (char*)d_ws;
  auto carve = [&](size_t bytes) -> void* {
    void* r = (void*)p;
    p += (bytes + 255) & ~(size_t)255;
    return r;
  };
  unsigned short* Bfh = (unsigned short*)carve((size_t)25 * 12 * 2 * 512 * 2);
  unsigned short* Bfl = (unsigned short*)carve((size_t)25 * 12 * 2 * 512 * 2);
  float* beff = (float*)carve(192 * 4);
  unsigned short* Xth = (unsigned short*)carve((size_t)4 * 68 * 72 * 64 * 2);
  unsigned short* Xtl = (unsigned short*)carve((size_t)4 * 68 * 72 * 64 * 2);
  float* Vm = (float*)carve(BN * 64 * 4);
  unsigned short* Qhi = (unsigned short*)carve(BN * 64 * 2);
  unsigned short* Qlo = (unsigned short*)carve(BN * 64 * 2);
  unsigned short* Khi = (unsigned short*)carve(BN * 64 * 2);
  unsigned short* Klo = (unsigned short*)carve(BN * 64 * 2);
  float* s_part = (float*)carve((size_t)4 * 8 * 4096 * 4);
  float* invs = (float*)carve(BN * 4);
  float* cs_part = (float*)carve((size_t)4 * 8 * 4096 * 4);
  int* topkbuf = (int*)carve(512 * 4);

  setup_kernel<<<350, 256, 0, stream>>>(x, w1, w3, w5, wq, wk, wv, b1, b3, b5, bq,
                                        bk, bv, Xth, Xtl, Bfh, Bfl, beff);
  fused_qkv_kernel<<<dim3(64, 4, 3), 256, 0, stream>>>(Xth, Xtl, Bfh, Bfl, beff, Qhi,
                                                       Qlo, Khi, Klo, Vm);
  qk_s_kernel<<<dim3(32, 8, 4), 256, 0, stream>>>(Qhi, Qlo, Khi, Klo, s_part);
  colsum_kernel2<<<dim3(32, 8, 4), 256, 0, stream>>>(Qhi, Qlo, Khi, Klo, s_part,
                                                     invs, cs_part);
  topk_kernel<<<4, 256, 0, stream>>>(cs_part, topkbuf);
  attn_out_kernel<<<dim3(128, 4), 256, 0, stream>>>(Qhi, Qlo, Khi, Klo, Vm, invs,
                                                    topkbuf, wo, bo, (float*)d_out);
}

// Round 24
// 153.698 us; speedup vs baseline: 1.1219x; 1.0189x over previous
//
#include <hip/hip_runtime.h>
#include <math.h>

#define N_PIX 4096
#define CCH 64

typedef __attribute__((ext_vector_type(8))) short short8;
typedef __attribute__((ext_vector_type(4))) float f32x4;
typedef __attribute__((ext_vector_type(16))) float f32x16;

#define EXP2C 0.18033688f  // 0.125 * log2(e)

// LDS tiles are [rows][68] floats; XOR-swizzle the 4-float granule by (row>>2)&7
// so that 4-row-strided b128 reads spread across bank groups (else 8-way conflict).
__device__ __forceinline__ int swz(int row, int col) {
  return row * 68 + (col ^ (((row >> 2) & 7) << 2));
}

__device__ __forceinline__ float fget(const float4& v, int j) {
  return ((const float*)&v)[j];
}

__device__ __forceinline__ unsigned short f2bf(float f) {
  unsigned u = __float_as_uint(f);
  unsigned r = (u + 0x7fff + ((u >> 16) & 1)) >> 16;
  return (unsigned short)r;
}
__device__ __forceinline__ float bf2f(unsigned short h) {
  return __uint_as_float((unsigned)h << 16);
}

// raw-rate exp2 (single v_exp_f32); inputs here are bounded (|z|<~8, lg2w ~ -12)
__device__ __forceinline__ float fexp2(float x) {
#if __has_builtin(__builtin_amdgcn_exp2f)
  return __builtin_amdgcn_exp2f(x);
#else
  return exp2f(x);
#endif
}

// async global->LDS, 16B per lane. Builtin path: LDS dest = wave-uniform base +
// lane*16 (m104); GLOBAL SOURCE IS PER-LANE - caller must add lane offset.
__device__ __forceinline__ void gll16(const unsigned short* g, unsigned short* lbase,
                                      int lane) {
#if __has_builtin(__builtin_amdgcn_global_load_lds)
  (void)lane;
  __builtin_amdgcn_global_load_lds(
      (const __attribute__((address_space(1))) void*)g,
      (__attribute__((address_space(3))) void*)lbase, 16, 0, 0);
#else
  *(short8*)(lbase + lane * 8) = *(const short8*)g;
#endif
}

// ---------------- setup: xpose (blocks 0..271) + weight prep (blocks 272..349) ------
__global__ __launch_bounds__(256) void setup_kernel(
    const float* __restrict__ x, const float* __restrict__ w1,
    const float* __restrict__ w3, const float* __restrict__ w5,
    const float* __restrict__ wq, const float* __restrict__ wk,
    const float* __restrict__ wv, const float* __restrict__ b1,
    const float* __restrict__ b3, const float* __restrict__ b5,
    const float* __restrict__ bq, const float* __restrict__ bk,
    const float* __restrict__ bv, unsigned short* __restrict__ Xth,
    unsigned short* __restrict__ Xtl, unsigned short* __restrict__ Bfh,
    unsigned short* __restrict__ Bfl, float* __restrict__ beff) {
  __shared__ char smem[2 * 64 * 68 * 4];  // union: prep At+Bt (34.8KB) / xpose t (16.6KB)
  const int tid = threadIdx.x;
  if (blockIdx.x < 272) {
    // ----- xpose slice: [b][c][y][x] fp32 -> Xt[b][68][72][64] bf16 hi/lo -----
    float(*t)[65] = (float(*)[65])smem;
    const int yp = blockIdx.x % 68;
    const int b = blockIdx.x / 68;
    const size_t rowbase = ((size_t)b * 68 + yp) * 72 * 64;  // ushort index
    short8 z8 = {0, 0, 0, 0, 0, 0, 0, 0};
    if (yp < 2 || yp >= 66) {
      short8* ph = (short8*)(Xth + rowbase);
      short8* pl = (short8*)(Xtl + rowbase);
      for (int v = tid; v < 576; v += 256) {  // 72*64/8
        ph[v] = z8;
        pl[v] = z8;
      }
      return;
    }
    const int y = yp - 2;
    for (int it = 0; it < 16; ++it) {
      const int v = it * 256 + tid;
      const int c = v >> 6, xx = v & 63;
      t[xx][c] = x[(((size_t)b * 64 + c) * 64 + y) * 64 + xx];
    }
    for (int s = tid; s < 64; s += 256) {
      const int col = s >> 3;
      const int xp = col < 2 ? col : col + 64;
      const size_t o = rowbase + (size_t)xp * 64 + (s & 7) * 8;
      *(short8*)(Xth + o) = z8;
      *(short8*)(Xtl + o) = z8;
    }
    __syncthreads();
    for (int it = 0; it < 16; ++it) {
      const int v = it * 256 + tid;
      const int xx = v >> 6, c = v & 63;
      const float val = t[xx][c];
      const unsigned short h = f2bf(val);
      const unsigned short lo = f2bf(val - bf2f(h));
      const int xp = xx + 2;
      const size_t idx = rowbase + (size_t)xp * 64 + (c ^ ((xp & 7) << 3));
      Xth[idx] = h;
      Xtl[idx] = lo;
    }
    return;
  }
  // ----- prep slice: fold conv weights into wq|wk|wv (+ beff at t==25) -----
  float* At = (float*)smem;                 // A[i][o] = wconv[o,i,tap]
  float* Bt = (float*)(smem + 64 * 68 * 4); // B[o][em] = Wsel[rowbase+o][em]
  const int idx78 = blockIdx.x - 272;
  const int which = idx78 % 3, t = idx78 / 3;
  const float* Wsel = which == 0 ? wq : (which == 1 ? wk : wv);
  const int tx = tid & 15, ty = tid >> 4;
  if (t == 25) {  // beff slice
    if (tid < 64) {
      const float* bsel = which == 0 ? bq : (which == 1 ? bk : bv);
      float s = bsel[tid];
      for (int row = 0; row < 192; ++row) {
        const float bc = row < 64 ? b1[row] : (row < 128 ? b3[row - 64] : b5[row - 128]);
        s += bc * Wsel[row * 64 + tid];
      }
      beff[which * 64 + tid] = s;
    }
    return;
  }
  const int ky = t / 5, kx = t % 5;
  const bool in3 = (ky >= 1 && ky <= 3 && kx >= 1 && kx <= 3);
  const bool c1 = (t == 12);
  const int t3 = (ky - 1) * 3 + (kx - 1);
  float acc[4][4];
#pragma unroll
  for (int i = 0; i < 4; ++i)
#pragma unroll
    for (int j = 0; j < 4; ++j) acc[i][j] = 0.f;
  const int npass = 1 + (in3 ? 1 : 0) + (c1 ? 1 : 0);
  for (int pass = 0; pass < npass; ++pass) {
    const int kind = pass == 0 ? 0 : (pass == 1 && in3 ? 1 : 2);
    const int rowbase = kind == 0 ? 128 : (kind == 1 ? 64 : 0);
    __syncthreads();
    for (int v = tid; v < 4096; v += 256) {
      const int i = v & 63, o = v >> 6;
      float a;
      if (kind == 0) a = w5[(size_t)(o * 64 + i) * 25 + t];
      else if (kind == 1) a = w3[(size_t)(o * 64 + i) * 9 + t3];
      else a = w1[o * 64 + i];
      At[swz(i, o)] = a;
    }
    for (int v = tid; v < 1024; v += 256) {
      const int row = v >> 4, c4 = (v & 15) * 4;
      *(float4*)&Bt[swz(row, c4)] = *(const float4*)(Wsel + (rowbase + row) * 64 + c4);
    }
    __syncthreads();
#pragma unroll
    for (int o4 = 0; o4 < 16; ++o4) {
      float4 a[4], b[4];
#pragma unroll
      for (int i = 0; i < 4; ++i) a[i] = *(const float4*)&At[swz(ty * 4 + i, o4 * 4)];
#pragma unroll
      for (int u = 0; u < 4; ++u) b[u] = *(const float4*)&Bt[swz(o4 * 4 + u, tx * 4)];
#pragma unroll
      for (int i = 0; i < 4; ++i)
#pragma unroll
        for (int j = 0; j < 4; ++j)
#pragma unroll
          for (int u = 0; u < 4; ++u)
            acc[i][j] = fmaf(fget(a[i], u), fget(b[u], j), acc[i][j]);
    }
  }
#pragma unroll
  for (int ii = 0; ii < 4; ++ii) {
    const int i = ty * 4 + ii;
    const int s = i >> 5, lg = (i >> 3) & 3, j = i & 7;
#pragma unroll
    for (int jj = 0; jj < 4; ++jj) {
      const int em = tx * 4 + jj;
      const int q = which * 4 + (em >> 4), lr = em & 15;
      const size_t off = ((size_t)(t * 12 + q) * 2 + s) * 512 + (lg * 16 + lr) * 8 + j;
      const float val = acc[ii][jj];
      const unsigned short h = f2bf(val);
      Bfh[off] = h;
      Bfl[off] = f2bf(val - bf2f(h));
    }
  }
}

// ---------------- fused im2col GEMM: Xt -> Q(hi/lo), K(hi/lo), V ----------------
// Grid (64 tiles, 4 b, 3 z): block 256 = 4 waves. Wave wv owns quadrant
// qd = z*4+wv x ALL 64 pixels; 768 blocks -> 3 blocks/CU hides B latency.
__global__ __launch_bounds__(256) void fused_qkv_kernel(
    const unsigned short* __restrict__ Xth, const unsigned short* __restrict__ Xtl,
    const unsigned short* __restrict__ Bfh, const unsigned short* __restrict__ Bfl,
    const float* __restrict__ beff, unsigned short* __restrict__ Qhi,
    unsigned short* __restrict__ Qlo, unsigned short* __restrict__ Khi,
    unsigned short* __restrict__ Klo, float* __restrict__ Vm) {
  __shared__ unsigned short Lh[192 * 64];  // [12 rows][16 px][64 ch] = 24KB
  __shared__ unsigned short Ll[192 * 64];
  const int b = blockIdx.y, sb = blockIdx.x;
  const int y0 = (sb >> 3) * 8, x0 = (sb & 7) * 8;
  const int tid = threadIdx.x, wv = tid >> 6, l = tid & 63;
  const int lr = l & 15, lg = l >> 4;
  const int qd = blockIdx.z * 4 + wv;  // this wave's output quadrant (0..11)
#pragma unroll
  for (int rr = 0; rr < 3; ++rr) {
    const int py = wv * 3 + rr;
    const size_t src = (((size_t)b * 68 + y0 + py) * 72 + x0) * 64 + (size_t)l * 8;
    gll16(Xth + src, &Lh[py * 1024], l);
    gll16(Xth + src + 512, &Lh[py * 1024 + 512], l);
    gll16(Xtl + src, &Ll[py * 1024], l);
    gll16(Xtl + src + 512, &Ll[py * 1024 + 512], l);
  }
  __syncthreads();
  f32x4 acc[4];
#pragma unroll
  for (int pg = 0; pg < 4; ++pg) acc[pg] = (f32x4){0.f, 0.f, 0.f, 0.f};
  for (int ky = 0; ky < 5; ++ky) {
    for (int kx = 0; kx < 5; ++kx) {
      const int t = ky * 5 + kx;
      const size_t f = ((size_t)(t * 12 + qd)) * 2;
      const short8 bh0 = *(const short8*)&Bfh[f * 512 + l * 8];
      const short8 bh1 = *(const short8*)&Bfh[(f + 1) * 512 + l * 8];
      const short8 bl0 = *(const short8*)&Bfl[f * 512 + l * 8];
      const short8 bl1 = *(const short8*)&Bfl[(f + 1) * 512 + l * 8];
#pragma unroll
      for (int pg = 0; pg < 4; ++pg) {
        const int p = pg * 16 + lr;
        const int prt = ((p >> 3) + ky) * 16 + (p & 7) + kx;
        const int rb = prt * 64, sw = (prt & 7) << 3;
        const short8 ah0 = *(const short8*)&Lh[rb + ((lg * 8) ^ sw)];
        const short8 ah1 = *(const short8*)&Lh[rb + ((32 + lg * 8) ^ sw)];
        const short8 al0 = *(const short8*)&Ll[rb + ((lg * 8) ^ sw)];
        const short8 al1 = *(const short8*)&Ll[rb + ((32 + lg * 8) ^ sw)];
        acc[pg] = __builtin_amdgcn_mfma_f32_16x16x32_bf16(ah0, bh0, acc[pg], 0, 0, 0);
        acc[pg] = __builtin_amdgcn_mfma_f32_16x16x32_bf16(ah1, bh1, acc[pg], 0, 0, 0);
        acc[pg] = __builtin_amdgcn_mfma_f32_16x16x32_bf16(al0, bh0, acc[pg], 0, 0, 0);
        acc[pg] = __builtin_amdgcn_mfma_f32_16x16x32_bf16(al1, bh1, acc[pg], 0, 0, 0);
        acc[pg] = __builtin_amdgcn_mfma_f32_16x16x32_bf16(ah0, bl0, acc[pg], 0, 0, 0);
        acc[pg] = __builtin_amdgcn_mfma_f32_16x16x32_bf16(ah1, bl1, acc[pg], 0, 0, 0);
      }
    }
  }
  const size_t base = (size_t)b * N_PIX;
  {
    const int e = qd * 16 + lr;
    const int which = e >> 6, em = e & 63;
    const float be = beff[e];
#pragma unroll
    for (int pg = 0; pg < 4; ++pg) {
#pragma unroll
      for (int r = 0; r < 4; ++r) {
        const int pp = pg * 16 + lg * 4 + r;
        const int n = (y0 + (pp >> 3)) * 64 + x0 + (pp & 7);
        const float val = acc[pg][r] + be;
        const size_t off = (base + n) * 64 + em;
        if (which == 2) {
          Vm[off] = val;
        } else {
          const unsigned short h = f2bf(val);
          const unsigned short lo = f2bf(val - bf2f(h));
          if (which == 0) {
            Qhi[off] = h;
            Qlo[off] = lo;
          } else {
            Khi[off] = h;
            Klo[off] = lo;
          }
        }
      }
    }
  }
}

// ---------------- sweep 1: row sums of exp(z), LDS-staged K (depth-1), 2-chain MFMA --
__global__ __launch_bounds__(256) void qk_s_kernel(
    const unsigned short* __restrict__ Qhi, const unsigned short* __restrict__ Qlo,
    const unsigned short* __restrict__ Khi, const unsigned short* __restrict__ Klo,
    float* __restrict__ s_part) {
  __shared__ unsigned short Kst[2][2][2048];  // [buf][hi/lo][32*64]
  const int b = blockIdx.z, kc = blockIdx.y, q0 = blockIdx.x * 128;
  const int tid = threadIdx.x, wv = tid >> 6, l = tid & 63;
  const int lr = l & 31, lh = l >> 5;
  const size_t base = (size_t)b * N_PIX;
  const size_t qoff = (base + q0 + wv * 32 + lr) * 64 + lh * 8;
  short8 qh[4], ql[4];
#pragma unroll
  for (int f = 0; f < 4; ++f) {
    qh[f] = *(const short8*)(Qhi + qoff + f * 16);
    ql[f] = *(const short8*)(Qlo + qoff + f * 16);
  }
  const int srow = tid >> 3;
  const int gcu = ((tid & 7) * 8) ^ ((srow & 7) << 3);
  const unsigned short* Ksh = Khi + (base + kc * 512 + srow) * 64 + gcu;
  const unsigned short* Ksl = Klo + (base + kc * 512 + srow) * 64 + gcu;
  float racc[16];
#pragma unroll
  for (int r = 0; r < 16; ++r) racc[r] = 0.f;

#define STAGE(bb, t)                                   \
  {                                                    \
    const size_t go_ = (size_t)(t) * 2048;             \
    gll16(Ksh + go_, &Kst[bb][0][wv * 512], l);        \
    gll16(Ksl + go_, &Kst[bb][1][wv * 512], l);        \
  }
// two independent accumulator chains (f=0,1 vs f=2,3) to break MFMA serial latency
#define COMP(bb)                                                                     \
  {                                                                                  \
    short8 kh_[4], kl_[4];                                                           \
    const int rb_ = lr * 64, sw_ = (lr & 7) << 3;                                    \
    _Pragma("unroll") for (int f = 0; f < 4; ++f) {                                  \
      const int c_ = rb_ + ((lh * 8 + f * 16) ^ sw_);                                \
      kh_[f] = *(const short8*)&Kst[bb][0][c_];                                      \
      kl_[f] = *(const short8*)&Kst[bb][1][c_];                                      \
    }                                                                                \
    f32x16 a0, a1;                                                                   \
    _Pragma("unroll") for (int r = 0; r < 16; ++r) { a0[r] = 0.f; a1[r] = 0.f; }     \
    a0 = __builtin_amdgcn_mfma_f32_32x32x16_bf16(qh[0], kh_[0], a0, 0, 0, 0);        \
    a1 = __builtin_amdgcn_mfma_f32_32x32x16_bf16(qh[2], kh_[2], a1, 0, 0, 0);        \
    a0 = __builtin_amdgcn_mfma_f32_32x32x16_bf16(qh[1], kh_[1], a0, 0, 0, 0);        \
    a1 = __builtin_amdgcn_mfma_f32_32x32x16_bf16(qh[3], kh_[3], a1, 0, 0, 0);        \
    a0 = __builtin_amdgcn_mfma_f32_32x32x16_bf16(ql[0], kh_[0], a0, 0, 0, 0);        \
    a1 = __builtin_amdgcn_mfma_f32_32x32x16_bf16(ql[2], kh_[2], a1, 0, 0, 0);        \
    a0 = __builtin_amdgcn_mfma_f32_32x32x16_bf16(ql[1], kh_[1], a0, 0, 0, 0);        \
    a1 = __builtin_amdgcn_mfma_f32_32x32x16_bf16(ql[3], kh_[3], a1, 0, 0, 0);        \
    a0 = __builtin_amdgcn_mfma_f32_32x32x16_bf16(qh[0], kl_[0], a0, 0, 0, 0);        \
    a1 = __builtin_amdgcn_mfma_f32_32x32x16_bf16(qh[2], kl_[2], a1, 0, 0, 0);        \
    a0 = __builtin_amdgcn_mfma_f32_32x32x16_bf16(qh[1], kl_[1], a0, 0, 0, 0);        \
    a1 = __builtin_amdgcn_mfma_f32_32x32x16_bf16(qh[3], kl_[3], a1, 0, 0, 0);        \
    _Pragma("unroll") for (int r = 0; r < 16; ++r)                                   \
        racc[r] += fexp2((a0[r] + a1[r]) * EXP2C);                                   \
  }

  STAGE(0, 0);
  __syncthreads();
  int bu = 0;
  for (int t = 0; t < 16; ++t) {
    if (t < 15) STAGE(bu ^ 1, t + 1);
    COMP(bu);
    __syncthreads();
    bu ^= 1;
  }
#undef STAGE
#undef COMP
#pragma unroll
  for (int r = 0; r < 16; ++r)
#pragma unroll
    for (int m = 1; m < 32; m <<= 1) racc[r] += __shfl_xor(racc[r], m);
  if (lr == 0) {
#pragma unroll
    for (int r = 0; r < 16; ++r) {
      const int row = (r & 3) + 8 * (r >> 2) + 4 * lh;
      s_part[((size_t)(b * 8 + kc) << 12) + q0 + wv * 32 + row] = racc[r];
    }
  }
}

// ---------------- sweep 2: weighted col sums + fused combine (grid 32x8x4) ---------
__global__ __launch_bounds__(256) void colsum_kernel2(
    const unsigned short* __restrict__ Qhi, const unsigned short* __restrict__ Qlo,
    const unsigned short* __restrict__ Khi, const unsigned short* __restrict__ Klo,
    const float* __restrict__ s_part, float* __restrict__ invs,
    float* __restrict__ cs_part) {
  __shared__ unsigned short Qst[2][2][2048];
  __shared__ float lg2wl[512];
  const int b = blockIdx.z, qc = blockIdx.y, k0 = blockIdx.x * 128;
  const int tid = threadIdx.x, wv = tid >> 6, l = tid & 63;
  const int lr = l & 31, lh = l >> 5;
  const size_t base = (size_t)b * N_PIX;
  const size_t koff = (base + k0 + wv * 32 + lr) * 64 + lh * 8;
  short8 kh[4], kl[4];
#pragma unroll
  for (int f = 0; f < 4; ++f) {
    kh[f] = *(const short8*)(Khi + koff + f * 16);
    kl[f] = *(const short8*)(Klo + koff + f * 16);
  }
  const int srow = tid >> 3;
  const int gcu = ((tid & 7) * 8) ^ ((srow & 7) << 3);
  const unsigned short* Qsh = Qhi + (base + qc * 512 + srow) * 64 + gcu;
  const unsigned short* Qsl = Qlo + (base + qc * 512 + srow) * 64 + gcu;
  float kacc[16];
#pragma unroll
  for (int r = 0; r < 16; ++r) kacc[r] = 0.f;

#define STAGE(bb, t)                                   \
  {                                                    \
    const size_t go_ = (size_t)(t) * 2048;             \
    gll16(Qsh + go_, &Qst[bb][0][wv * 512], l);        \
    gll16(Qsl + go_, &Qst[bb][1][wv * 512], l);        \
  }
#define COMP(bb, t_)                                                                 \
  {                                                                                  \
    const float lw_ = lg2wl[(t_) * 32 + lr];                                         \
    short8 qh_[4], ql_[4];                                                           \
    const int rb_ = lr * 64, sw_ = (lr & 7) << 3;                                    \
    _Pragma("unroll") for (int f = 0; f < 4; ++f) {                                  \
      const int c_ = rb_ + ((lh * 8 + f * 16) ^ sw_);                                \
      qh_[f] = *(const short8*)&Qst[bb][0][c_];                                      \
      ql_[f] = *(const short8*)&Qst[bb][1][c_];                                      \
    }                                                                                \
    f32x16 a0, a1;                                                                   \
    _Pragma("unroll") for (int r = 0; r < 16; ++r) { a0[r] = 0.f; a1[r] = 0.f; }     \
    a0 = __builtin_amdgcn_mfma_f32_32x32x16_bf16(kh[0], qh_[0], a0, 0, 0, 0);        \
    a1 = __builtin_amdgcn_mfma_f32_32x32x16_bf16(kh[2], qh_[2], a1, 0, 0, 0);        \
    a0 = __builtin_amdgcn_mfma_f32_32x32x16_bf16(kh[1], qh_[1], a0, 0, 0, 0);        \
    a1 = __builtin_amdgcn_mfma_f32_32x32x16_bf16(kh[3], qh_[3], a1, 0, 0, 0);        \
    a0 = __builtin_amdgcn_mfma_f32_32x32x16_bf16(kl[0], qh_[0], a0, 0, 0, 0);        \
    a1 = __builtin_amdgcn_mfma_f32_32x32x16_bf16(kl[2], qh_[2], a1, 0, 0, 0);        \
    a0 = __builtin_amdgcn_mfma_f32_32x32x16_bf16(kl[1], qh_[1], a0, 0, 0, 0);        \
    a1 = __builtin_amdgcn_mfma_f32_32x32x16_bf16(kl[3], qh_[3], a1, 0, 0, 0);        \
    a0 = __builtin_amdgcn_mfma_f32_32x32x16_bf16(kh[0], ql_[0], a0, 0, 0, 0);        \
    a1 = __builtin_amdgcn_mfma_f32_32x32x16_bf16(kh[2], ql_[2], a1, 0, 0, 0);        \
    a0 = __builtin_amdgcn_mfma_f32_32x32x16_bf16(kh[1], ql_[1], a0, 0, 0, 0);        \
    a1 = __builtin_amdgcn_mfma_f32_32x32x16_bf16(kh[3], ql_[3], a1, 0, 0, 0);        \
    _Pragma("unroll") for (int r = 0; r < 16; ++r)                                   \
        kacc[r] += fexp2(fmaf(a0[r] + a1[r], EXP2C, lw_));                           \
  }

  STAGE(0, 0);
  // fused combine: lg2w for this block's 512 q-rows (+ invs from x==0 blocks)
  for (int v = tid; v < 512; v += 256) {
    const int q = qc * 512 + v;
    float s = 0.f;
#pragma unroll
    for (int c = 0; c < 8; ++c) s += s_part[((size_t)(b * 8 + c) << 12) + q];
    lg2wl[v] = -__log2f(s);
    if (blockIdx.x == 0) invs[b * N_PIX + q] = 1.f / s;
  }
  __syncthreads();
  int bu = 0;
  for (int t = 0; t < 16; ++t) {
    if (t < 15) STAGE(bu ^ 1, t + 1);
    COMP(bu, t);
    __syncthreads();
    bu ^= 1;
  }
#undef STAGE
#undef COMP
#pragma unroll
  for (int r = 0; r < 16; ++r)
#pragma unroll
    for (int m = 1; m < 32; m <<= 1) kacc[r] += __shfl_xor(kacc[r], m);
  if (lr == 0) {
#pragma unroll
    for (int r = 0; r < 16; ++r) {
      const int row = (r & 3) + 8 * (r >> 2) + 4 * lh;
      cs_part[((size_t)(b * 8 + qc) << 12) + k0 + wv * 32 + row] = kacc[r];
    }
  }
}

// ---------------- top-128 per batch: deterministic 4-pass radix select ----------------
// Wave-level shfl scans replace Hillis-Steele LDS scans (~80 barriers -> ~20).
// Selection semantics identical: threshold T, all keys > T, lowest-index ties.
__global__ __launch_bounds__(256) void topk_kernel(const float* __restrict__ cs_part,
                                                   int* __restrict__ topk) {
  __shared__ unsigned keys[4096];
  __shared__ unsigned hist[256];
  __shared__ unsigned wsum[4];
  __shared__ unsigned selB, selNeed;
  const int b = blockIdx.x, tid = threadIdx.x;
  const int lane = tid & 63, w = tid >> 6;
  for (int v = tid; v < 4096; v += 256) {
    float s = 0.f;
#pragma unroll
    for (int qc = 0; qc < 8; ++qc) s += cs_part[((size_t)(b * 8 + qc) << 12) + v];
    unsigned u = __float_as_uint(s);
    keys[v] = (u & 0x80000000u) ? ~u : (u | 0x80000000u);
  }
  unsigned need = 128, prefix = 0;
  __syncthreads();
  for (int d = 3; d >= 0; --d) {
    const int shift = d * 8;
    hist[tid] = 0;
    __syncthreads();
    for (int v = tid; v < 4096; v += 256) {
      const unsigned k = keys[v];
      if (d == 3 || (k >> (shift + 8)) == prefix)
        atomicAdd(&hist[(k >> shift) & 255], 1u);
    }
    __syncthreads();
    const unsigned hv = hist[tid];
    // inclusive suffix scan within wave (64 buckets)
    unsigned s = hv;
#pragma unroll
    for (int off = 1; off < 64; off <<= 1) {
      const unsigned o = __shfl_down(s, off);
      if (lane + off < 64) s += o;
    }
    if (lane == 0) wsum[w] = s;  // total of this wave's bucket range
    __syncthreads();
    unsigned sufGe = s;
#pragma unroll
    for (int w2 = 0; w2 < 4; ++w2)
      if (w2 > w) sufGe += wsum[w2];
    const unsigned sufGt = sufGe - hv;
    if (sufGt < need && need <= sufGe) {
      selB = (unsigned)tid;
      selNeed = need - sufGt;
    }
    __syncthreads();
    prefix = (prefix << 8) | selB;
    need = selNeed;
    __syncthreads();
  }
  const unsigned T = prefix;
  // per-thread counts over its contiguous 16-element chunk
  unsigned gtc = 0, eqc = 0;
#pragma unroll
  for (int j = 0; j < 16; ++j) {
    const unsigned k = keys[tid * 16 + j];
    gtc += (k > T);
    eqc += (k == T);
  }
  // inclusive prefix scan (packed) via wave shfl + cross-wave combine
  const unsigned pv = (gtc << 16) | eqc;
  unsigned ps = pv;
#pragma unroll
  for (int off = 1; off < 64; off <<= 1) {
    const unsigned o = __shfl_up(ps, off);
    if (lane >= off) ps += o;
  }
  if (lane == 63) wsum[w] = ps;  // wave totals
  __syncthreads();
  unsigned incl = ps;
  unsigned tot = 0;
#pragma unroll
  for (int w2 = 0; w2 < 4; ++w2) {
    if (w2 < w) incl += wsum[w2];
    tot += wsum[w2];
  }
  const unsigned gBase = (incl >> 16) - gtc;
  const unsigned eBase = (incl & 0xffffu) - eqc;
  const unsigned nGt = tot >> 16;  // total greater-than count = 128 - need
  unsigned g = 0, e = 0;
#pragma unroll
  for (int j = 0; j < 16; ++j) {
    const int idx = tid * 16 + j;
    const unsigned k = keys[idx];
    if (k > T) {
      topk[b * 128 + gBase + g] = idx;
      ++g;
    } else if (k == T) {
      if (eBase + e < need) topk[b * 128 + nGt + eBase + e] = idx;
      ++e;
    }
  }
}

// ---------------- masked attention output + fused final projection ----------------
// 32 q-rows per block (grid 128x4 = 512 blocks, LDS 69.9KB -> 2 blocks/CU).
__global__ __launch_bounds__(256) void attn_out_kernel(
    const unsigned short* __restrict__ Qhp, const unsigned short* __restrict__ Qlp,
    const unsigned short* __restrict__ Khp, const unsigned short* __restrict__ Klp,
    const float* __restrict__ Vm, const float* __restrict__ invs,
    const int* __restrict__ topkb, const float* __restrict__ wo,
    const float* __restrict__ bo, float* __restrict__ dout) {
  __shared__ float Qld[32 * 68], Kld[64 * 68], Vt[64 * 68], Pl[32 * 68], Wl[64 * 68];
  __shared__ int sidx[64];
  const int b = blockIdx.y, q0 = blockIdx.x * 32;
  const int tid = threadIdx.x, tx = tid & 15, ty = tid >> 4;
  const size_t base = (size_t)b * N_PIX;
  for (int v = tid; v < 512; v += 256) {
    int row = v >> 4, c4 = (v & 15) * 4;
    size_t off = (base + q0 + row) * 64 + c4;
    ushort4 h = *(const ushort4*)(Qhp + off);
    ushort4 lo = *(const ushort4*)(Qlp + off);
    float4 f;
    f.x = bf2f(h.x) + bf2f(lo.x);
    f.y = bf2f(h.y) + bf2f(lo.y);
    f.z = bf2f(h.z) + bf2f(lo.z);
    f.w = bf2f(h.w) + bf2f(lo.w);
    *(float4*)&Qld[swz(row, c4)] = f;
  }
  for (int v = tid; v < 1024; v += 256) {
    int row = v >> 4, c4 = (v & 15) * 4;
    *(float4*)&Wl[swz(row, c4)] = *(const float4*)(wo + row * 64 + c4);
  }
  float is[2];
#pragma unroll
  for (int i = 0; i < 2; ++i) is[i] = invs[base + q0 + ty * 2 + i];
  float acc[2][4];
#pragma unroll
  for (int i = 0; i < 2; ++i)
#pragma unroll
    for (int j = 0; j < 4; ++j) acc[i][j] = 0.f;
  for (int ch = 0; ch < 2; ++ch) {
    __syncthreads();
    if (tid < 64) sidx[tid] = topkb[b * 128 + ch * 64 + tid];
    __syncthreads();
    for (int v = tid; v < 1024; v += 256) {
      int row = v >> 4, c4 = (v & 15) * 4;
      size_t off = (base + sidx[row]) * 64 + c4;
      ushort4 h = *(const ushort4*)(Khp + off);
      ushort4 lo = *(const ushort4*)(Klp + off);
      float4 f;
      f.x = bf2f(h.x) + bf2f(lo.x);
      f.y = bf2f(h.y) + bf2f(lo.y);
      f.z = bf2f(h.z) + bf2f(lo.z);
      f.w = bf2f(h.w) + bf2f(lo.w);
      *(float4*)&Kld[swz(row, c4)] = f;
    }
    for (int v = tid; v < 4096; v += 256) {
      int row = v >> 6, c = v & 63;
      Vt[swz(c, row)] = Vm[(base + sidx[row]) * 64 + c];
    }
    __syncthreads();
    float z[2][4];
#pragma unroll
    for (int i = 0; i < 2; ++i)
#pragma unroll
      for (int j = 0; j < 4; ++j) z[i][j] = 0.f;
#pragma unroll
    for (int e4 = 0; e4 < 16; ++e4) {
      float4 qa[2], ka[4];
#pragma unroll
      for (int i = 0; i < 2; ++i) qa[i] = *(const float4*)&Qld[swz(ty * 2 + i, e4 * 4)];
#pragma unroll
      for (int j = 0; j < 4; ++j) ka[j] = *(const float4*)&Kld[swz(tx * 4 + j, e4 * 4)];
#pragma unroll
      for (int i = 0; i < 2; ++i)
#pragma unroll
        for (int j = 0; j < 4; ++j)
#pragma unroll
          for (int u = 0; u < 4; ++u)
            z[i][j] = fmaf(fget(qa[i], u), fget(ka[j], u), z[i][j]);
    }
#pragma unroll
    for (int i = 0; i < 2; ++i)
#pragma unroll
      for (int j = 0; j < 4; ++j)
        Pl[swz(ty * 2 + i, tx * 4 + j)] = __expf(z[i][j] * 0.125f) * is[i];
    __syncthreads();
#pragma unroll
    for (int k4 = 0; k4 < 16; ++k4) {
      float4 pr[2], vr[4];
#pragma unroll
      for (int i = 0; i < 2; ++i) pr[i] = *(const float4*)&Pl[swz(ty * 2 + i, k4 * 4)];
#pragma unroll
      for (int j = 0; j < 4; ++j) vr[j] = *(const float4*)&Vt[swz(tx * 4 + j, k4 * 4)];
#pragma unroll
      for (int i = 0; i < 2; ++i)
#pragma unroll
        for (int j = 0; j < 4; ++j)
#pragma unroll
          for (int u = 0; u < 4; ++u)
            acc[i][j] = fmaf(fget(pr[i], u), fget(vr[j], u), acc[i][j]);
    }
  }
  __syncthreads();
#pragma unroll
  for (int i = 0; i < 2; ++i)
#pragma unroll
    for (int j = 0; j < 4; ++j) Pl[swz(ty * 2 + i, tx * 4 + j)] = acc[i][j];
  __syncthreads();
  float yacc[2][4];
#pragma unroll
  for (int i = 0; i < 2; ++i)
#pragma unroll
    for (int j = 0; j < 4; ++j) yacc[i][j] = 0.f;
#pragma unroll
  for (int e4 = 0; e4 < 16; ++e4) {
    float4 a[2], wr[4];
#pragma unroll
    for (int i = 0; i < 2; ++i) a[i] = *(const float4*)&Pl[swz(ty * 2 + i, e4 * 4)];
#pragma unroll
    for (int u = 0; u < 4; ++u) wr[u] = *(const float4*)&Wl[swz(e4 * 4 + u, tx * 4)];
#pragma unroll
    for (int i = 0; i < 2; ++i)
#pragma unroll
      for (int j = 0; j < 4; ++j)
#pragma unroll
        for (int u = 0; u < 4; ++u)
          yacc[i][j] = fmaf(fget(a[i], u), fget(wr[u], j), yacc[i][j]);
  }
  __syncthreads();
#pragma unroll
  for (int i = 0; i < 2; ++i)
#pragma unroll
    for (int j = 0; j < 4; ++j)
      Qld[swz(ty * 2 + i, tx * 4 + j)] = yacc[i][j] + bo[tx * 4 + j];
  __syncthreads();
  for (int v = tid; v < 2048; v += 256) {
    int c = v >> 5, nl = v & 31;
    dout[((size_t)b * 64 + c) * 4096 + q0 + nl] = Qld[swz(nl, c)];
  }
}

extern "C" void kernel_launch(void* const* d_in, const int* in_sizes, int n_in,
                              void* d_out, int out_size, void* d_ws, size_t ws_size,
                              hipStream_t stream) {
  const float* x = (const float*)d_in[0];
  const float* w1 = (const float*)d_in[1];
  const float* b1 = (const float*)d_in[2];
  const float* w3 = (const float*)d_in[3];
  const float* b3 = (const float*)d_in[4];
  const float* w5 = (const float*)d_in[5];
  const float* b5 = (const float*)d_in[6];
  const float* wq = (const float*)d_in[7];
  const float* bq = (const float*)d_in[8];
  const float* wk = (const float*)d_in[9];
  const float* bk = (const float*)d_in[10];
  const float* wv = (const float*)d_in[11];
  const float* bv = (const float*)d_in[12];
  const float* wo = (const float*)d_in[13];
  const float* bo = (const float*)d_in[14];

  const size_t BN = (size_t)4 * N_PIX;  // 16384
  char* p = (char*)d_ws;
  auto carve = [&](size_t bytes) -> void* {
    void* r = (void*)p;
    p += (bytes + 255) & ~(size_t)255;
    return r;
  };
  unsigned short* Bfh = (unsigned short*)carve((size_t)25 * 12 * 2 * 512 * 2);
  unsigned short* Bfl = (unsigned short*)carve((size_t)25 * 12 * 2 * 512 * 2);
  float* beff = (float*)carve(192 * 4);
  unsigned short* Xth = (unsigned short*)carve((size_t)4 * 68 * 72 * 64 * 2);
  unsigned short* Xtl = (unsigned short*)carve((size_t)4 * 68 * 72 * 64 * 2);
  float* Vm = (float*)carve(BN * 64 * 4);
  unsigned short* Qhi = (unsigned short*)carve(BN * 64 * 2);
  unsigned short* Qlo = (unsigned short*)carve(BN * 64 * 2);
  unsigned short* Khi = (unsigned short*)carve(BN * 64 * 2);
  unsigned short* Klo = (unsigned short*)carve(BN * 64 * 2);
  float* s_part = (float*)carve((size_t)4 * 8 * 4096 * 4);
  float* invs = (float*)carve(BN * 4);
  float* cs_part = (float*)carve((size_t)4 * 8 * 4096 * 4);
  int* topkbuf = (int*)carve(512 * 4);

  setup_kernel<<<350, 256, 0, stream>>>(x, w1, w3, w5, wq, wk, wv, b1, b3, b5, bq,
                                        bk, bv, Xth, Xtl, Bfh, Bfl, beff);
  fused_qkv_kernel<<<dim3(64, 4, 3), 256, 0, stream>>>(Xth, Xtl, Bfh, Bfl, beff, Qhi,
                                                       Qlo, Khi, Klo, Vm);
  qk_s_kernel<<<dim3(32, 8, 4), 256, 0, stream>>>(Qhi, Qlo, Khi, Klo, s_part);
  colsum_kernel2<<<dim3(32, 8, 4), 256, 0, stream>>>(Qhi, Qlo, Khi, Klo, s_part,
                                                     invs, cs_part);
  topk_kernel<<<4, 256, 0, stream>>>(cs_part, topkbuf);
  attn_out_kernel<<<dim3(128, 4), 256, 0, stream>>>(Qhi, Qlo, Khi, Klo, Vm, invs,
                                                    topkbuf, wo, bo, (float*)d_out);
}